// Round 7
// baseline (539.297 us; speedup 1.0000x reference)
//
#include <hip/hip_runtime.h>
#include <hip/hip_bf16.h>

// GNN attention layer: edge logits -> segment softmax(dst) -> weighted gather of
// hv=x@Wproj.T -> elu -> GRUCell(context, x) -> relu.
// V=50000, E=800000, D=H=128. Inputs f32, OUTPUT f32, src/dst int32. (R6 PASS)
//
// R7 optimization round (baseline 446.5 us, gru 117 us @ MfmaUtil 3.2%):
//  - gru/node_pre: TM=4 row-tiles per wave; each weight fragment load feeds 4
//    MFMAs (was 1:1 load:MFMA, pure L2-latency-bound). Gate math moved inside
//    the j-loop to keep accumulators at 64 VGPRs.
//  - scan: thread-sequential partials + single 1024-wide LDS scan (was 49
//    serialized Hillis-Steele passes).
//  - aggregate: 4x unrolled gather loop (4 rows in flight).

#define V_NODES 50000
#define E_EDGES 800000
#define D_FEAT  128
#define NTILE   3125          // V/16
#define TM      4             // row-tiles per wave in MFMA kernels

typedef short bf16x8 __attribute__((ext_vector_type(8)));  // 8 bf16 in 4 VGPRs
typedef float f32x4  __attribute__((ext_vector_type(4)));
typedef unsigned short u16x4 __attribute__((ext_vector_type(4)));

// small-tensor bf16 pool element offsets
#define OFF_WEDGE 0
#define OFF_WPROJ 256
#define OFF_WIH   16640
#define OFF_WHH   65792
#define OFF_BEDGE 114944
#define OFF_BPROJ 114945
#define OFF_BIH   115073
#define OFF_BHH   115457
#define SMALL_TOTAL 115841

// ---- device-global scratch (~46 MB; immune to ws_size) ----
__device__ int   g_is_bf16;
__device__ float g_pd[V_NODES];
__device__ float g_ps[V_NODES];
__device__ int   g_counts[V_NODES];
__device__ int   g_row_off[V_NODES + 1];
__device__ int   g_cursor[V_NODES];
__device__ int   g_s_src[E_EDGES];
__device__ float g_s_val[E_EDGES];
__device__ __attribute__((aligned(16))) unsigned short g_xbf[V_NODES * D_FEAT];
__device__ __attribute__((aligned(16))) unsigned short g_wsmall[SMALL_TOTAL + 15];
__device__ __attribute__((aligned(16))) unsigned short g_hv[V_NODES * D_FEAT];
__device__ __attribute__((aligned(16))) unsigned short g_ctx[V_NODES * D_FEAT];

static __device__ __forceinline__ float b2f(unsigned short u) {
  union { unsigned int i; float f; } v; v.i = ((unsigned int)u) << 16; return v.f;
}
static __device__ __forceinline__ unsigned short f2b(float f) {
  unsigned int i = __float_as_uint(f);
  unsigned int r = (i + 0x7FFFu + ((i >> 16) & 1u)) >> 16;  // RNE (NaN stays NaN)
  return (unsigned short)r;
}
static __device__ __forceinline__ bf16x8 load_frag(const unsigned short* p) {
  return *reinterpret_cast<const bf16x8*>(p);  // 16B-aligned vector load
}

// ---------------- P: dtype probe on x ----------------------------------------
__global__ void probe_kernel(const unsigned int* __restrict__ x)
{
  __shared__ int cnt;
  if (threadIdx.x == 0) cnt = 0;
  __syncthreads();
  const unsigned int w  = x[threadIdx.x];
  const unsigned int lo = w & 0xFFFFu;
  const unsigned int ex = (lo >> 7) & 0xFFu;
  if (lo != 0u && ex >= 118u && ex <= 132u) atomicAdd(&cnt, 1);
  __syncthreads();
  if (threadIdx.x == 0) g_is_bf16 = (cnt >= 200) ? 1 : 0;
}

// ---------------- C1: convert x (4 elems/thread) ------------------------------
__global__ void conv_x_kernel(const void* __restrict__ x)
{
  const int t = blockIdx.x * blockDim.x + threadIdx.x;
  if (t >= V_NODES * D_FEAT / 4) return;
  if (g_is_bf16) {
    reinterpret_cast<u16x4*>(g_xbf)[t] = reinterpret_cast<const u16x4*>(x)[t];
  } else {
    const float4 v = reinterpret_cast<const float4*>(x)[t];
    u16x4 o; o.x = f2b(v.x); o.y = f2b(v.y); o.z = f2b(v.z); o.w = f2b(v.w);
    reinterpret_cast<u16x4*>(g_xbf)[t] = o;
  }
}

// ---------------- C2: convert all small tensors -------------------------------
__global__ void conv_small_kernel(
    const void* p0, const void* p1, const void* p2, const void* p3,
    const void* p4, const void* p5, const void* p6, const void* p7)
{
  const int i = blockIdx.x * blockDim.x + threadIdx.x;
  if (i >= SMALL_TOTAL) return;
  const int offs[9] = {OFF_WEDGE, OFF_WPROJ, OFF_WIH, OFF_WHH,
                       OFF_BEDGE, OFF_BPROJ, OFF_BIH, OFF_BHH, SMALL_TOTAL};
  const void* ps[8] = {p0, p1, p2, p3, p4, p5, p6, p7};
  int r = 0;
#pragma unroll
  for (int k = 0; k < 8; k++) if (i >= offs[k]) r = k;
  const int j = i - offs[r];
  const unsigned short v = g_is_bf16
      ? reinterpret_cast<const unsigned short*>(ps[r])[j]
      : f2b(reinterpret_cast<const float*>(ps[r])[j]);
  g_wsmall[i] = v;
}

// ---------------- K0: zero counts --------------------------------------------
__global__ void zero_counts_kernel() {
  int i = blockIdx.x * blockDim.x + threadIdx.x;
  if (i < V_NODES) g_counts[i] = 0;
}

// ---------------- K1: hv = x@Wproj.T + b_proj; pd; ps  (TM tiles/wave) --------
__global__ __launch_bounds__(64, 1) void node_pre_kernel()
{
  const int lane  = threadIdx.x;
  const int col   = lane & 15;     // A: m index; C/D: n index
  const int quad  = lane >> 4;
  const int tile0 = blockIdx.x * TM;
  const unsigned short* W_edge = g_wsmall + OFF_WEDGE;
  const unsigned short* W_proj = g_wsmall + OFF_WPROJ;

  bf16x8 a[TM][4];
#pragma unroll
  for (int tt = 0; tt < TM; tt++) {
    const int tile = tile0 + tt;
    const int arow = (tile < NTILE) ? tile * 16 + col : col;
#pragma unroll
    for (int kk = 0; kk < 4; kk++)
      a[tt][kk] = load_frag(g_xbf + arow * D_FEAT + kk * 32 + quad * 8);
  }

  f32x4 acc[TM][8];
  f32x4 acce[TM];
#pragma unroll
  for (int tt = 0; tt < TM; tt++) {
    acce[tt][0]=0.f; acce[tt][1]=0.f; acce[tt][2]=0.f; acce[tt][3]=0.f;
#pragma unroll
    for (int j = 0; j < 8; j++) {
      acc[tt][j][0]=0.f; acc[tt][j][1]=0.f; acc[tt][j][2]=0.f; acc[tt][j][3]=0.f;
    }
  }

#pragma unroll
  for (int kk = 0; kk < 4; kk++) {
    bf16x8 be = {0,0,0,0,0,0,0,0};
    if (col < 2)  // n=0 -> w_dst, n=1 -> w_src
      be = load_frag(W_edge + col * D_FEAT + kk * 32 + quad * 8);
#pragma unroll
    for (int tt = 0; tt < TM; tt++)
      acce[tt] = __builtin_amdgcn_mfma_f32_16x16x32_bf16(a[tt][kk], be, acce[tt], 0, 0, 0);
#pragma unroll
    for (int j = 0; j < 8; j++) {
      bf16x8 b = load_frag(W_proj + (16 * j + col) * D_FEAT + kk * 32 + quad * 8);
#pragma unroll
      for (int tt = 0; tt < TM; tt++)
        acc[tt][j] = __builtin_amdgcn_mfma_f32_16x16x32_bf16(a[tt][kk], b, acc[tt][j], 0, 0, 0);
    }
  }

#pragma unroll
  for (int tt = 0; tt < TM; tt++) {
    const int tile = tile0 + tt;
    if (tile >= NTILE) break;
#pragma unroll
    for (int j = 0; j < 8; j++) {
      const int h = 16 * j + col;
      const float bp = b2f(g_wsmall[OFF_BPROJ + h]);
#pragma unroll
      for (int r = 0; r < 4; r++) {
        const int vrow = tile * 16 + quad * 4 + r;
        g_hv[vrow * D_FEAT + h] = f2b(acc[tt][j][r] + bp);
      }
    }
    if (col == 0) {
#pragma unroll
      for (int r = 0; r < 4; r++) g_pd[tile * 16 + quad * 4 + r] = acce[tt][r];
    } else if (col == 1) {
#pragma unroll
      for (int r = 0; r < 4; r++) g_ps[tile * 16 + quad * 4 + r] = acce[tt][r];
    }
  }
}

// ---------------- K2: histogram of dst ---------------------------------------
__global__ void hist_kernel(const int* __restrict__ dst, int E)
{
  int e = blockIdx.x * blockDim.x + threadIdx.x;
  if (e < E) atomicAdd(&g_counts[dst[e]], 1);
}

// ---------------- K3: scan (sequential partials + one LDS scan) ---------------
__global__ __launch_bounds__(1024) void scan_kernel()
{
  __shared__ int lds[1024];
  const int tid = threadIdx.x;
  const int PER = 49;                       // ceil(50000/1024)
  const int base = tid * PER;
  int s = 0;
  for (int k = 0; k < PER; k++) {
    const int idx = base + k;
    if (idx < V_NODES) s += g_counts[idx];
  }
  lds[tid] = s;
  __syncthreads();
  for (int off = 1; off < 1024; off <<= 1) {
    int t = (tid >= off) ? lds[tid - off] : 0;
    __syncthreads();
    lds[tid] += t;
    __syncthreads();
  }
  int run = lds[tid] - s;                   // exclusive prefix of this thread
  for (int k = 0; k < PER; k++) {
    const int idx = base + k;
    if (idx < V_NODES) {
      g_row_off[idx] = run;
      g_cursor[idx]  = run;
      run += g_counts[idx];
    }
  }
  if (tid == 1023) g_row_off[V_NODES] = run;
}

// ---------------- K4: edge scatter (CSR fill + softmax numerator) ------------
__global__ void edge_scatter_kernel(
    const int* __restrict__ src, const int* __restrict__ dst, int E)
{
  int e = blockIdx.x * blockDim.x + threadIdx.x;
  if (e >= E) return;
  const int d = dst[e], sn = src[e];
  float logit = g_pd[d] + g_ps[sn] + b2f(g_wsmall[OFF_BEDGE]);
  logit = (logit >= 0.f) ? logit : 0.01f * logit;           // LeakyReLU(0.01)
  const float w = __expf(logit);                            // no max-sub: cancels
  const int pos = atomicAdd(&g_cursor[d], 1);
  g_s_src[pos] = sn;
  g_s_val[pos] = w;
}

// ---------------- K5: per-dst aggregation + elu -> context (bf16) ------------
__global__ __launch_bounds__(64) void aggregate_kernel()
{
  const int v = blockIdx.x;
  const int lane = threadIdx.x;        // lane handles cols 2*lane, 2*lane+1
  const int beg = g_row_off[v], end = g_row_off[v + 1];
  float accx = 0.f, accy = 0.f, ssum = 0.f;
  int i = beg;
  for (; i + 4 <= end; i += 4) {       // 4 gathers in flight
    const int   s0 = g_s_src[i],     s1 = g_s_src[i + 1],
                s2 = g_s_src[i + 2], s3 = g_s_src[i + 3];
    const float w0 = g_s_val[i],     w1 = g_s_val[i + 1],
                w2 = g_s_val[i + 2], w3 = g_s_val[i + 3];
    const unsigned int p0 = *reinterpret_cast<const unsigned int*>(g_hv + s0 * D_FEAT + lane * 2);
    const unsigned int p1 = *reinterpret_cast<const unsigned int*>(g_hv + s1 * D_FEAT + lane * 2);
    const unsigned int p2 = *reinterpret_cast<const unsigned int*>(g_hv + s2 * D_FEAT + lane * 2);
    const unsigned int p3 = *reinterpret_cast<const unsigned int*>(g_hv + s3 * D_FEAT + lane * 2);
    ssum += (w0 + w1) + (w2 + w3);
    accx += w0 * b2f((unsigned short)(p0 & 0xFFFFu)) + w1 * b2f((unsigned short)(p1 & 0xFFFFu))
          + w2 * b2f((unsigned short)(p2 & 0xFFFFu)) + w3 * b2f((unsigned short)(p3 & 0xFFFFu));
    accy += w0 * b2f((unsigned short)(p0 >> 16)) + w1 * b2f((unsigned short)(p1 >> 16))
          + w2 * b2f((unsigned short)(p2 >> 16)) + w3 * b2f((unsigned short)(p3 >> 16));
  }
  for (; i < end; i++) {
    const int sn  = g_s_src[i];
    const float w = g_s_val[i];
    ssum += w;
    const unsigned int pair =
        *reinterpret_cast<const unsigned int*>(g_hv + sn * D_FEAT + lane * 2);
    accx += w * b2f((unsigned short)(pair & 0xFFFFu));
    accy += w * b2f((unsigned short)(pair >> 16));
  }
  const float inv = (end > beg) ? (1.0f / ssum) : 0.0f;     // empty segment -> c=0
  float c0 = accx * inv, c1 = accy * inv;
  c0 = (c0 > 0.f) ? c0 : (__expf(c0) - 1.f);                // elu
  c1 = (c1 > 0.f) ? c1 : (__expf(c1) - 1.f);
  const unsigned int outp = ((unsigned int)f2b(c1) << 16) | (unsigned int)f2b(c0);
  *reinterpret_cast<unsigned int*>(g_ctx + v * D_FEAT + lane * 2) = outp;
}

// ---------------- K6: GRUCell + relu, TM tiles/wave, f32 out ------------------
__global__ __launch_bounds__(64, 1) void gru_kernel(const float* __restrict__ xf32,
                                                    float* __restrict__ out)
{
  const int lane  = threadIdx.x;
  const int col   = lane & 15;
  const int quad  = lane >> 4;
  const int tile0 = blockIdx.x * TM;
  const unsigned short* W_ih = g_wsmall + OFF_WIH;
  const unsigned short* W_hh = g_wsmall + OFF_WHH;
  const int isb = g_is_bf16;

  bf16x8 ax[TM][4], ac[TM][4];
#pragma unroll
  for (int tt = 0; tt < TM; tt++) {
    const int tile = tile0 + tt;
    const int arow = (tile < NTILE) ? tile * 16 + col : col;
#pragma unroll
    for (int kk = 0; kk < 4; kk++) {
      ax[tt][kk] = load_frag(g_xbf + arow * D_FEAT + kk * 32 + quad * 8);
      ac[tt][kk] = load_frag(g_ctx + arow * D_FEAT + kk * 32 + quad * 8);
    }
  }

#pragma unroll
  for (int j = 0; j < 8; j++) {
    const int h = 16 * j + col;
    f32x4 racc[TM], zacc[TM], niacc[TM], nhacc[TM];
    {
      const float br = b2f(g_wsmall[OFF_BIH + h])       + b2f(g_wsmall[OFF_BHH + h]);
      const float bz = b2f(g_wsmall[OFF_BIH + 128 + h]) + b2f(g_wsmall[OFF_BHH + 128 + h]);
      const float bn = b2f(g_wsmall[OFF_BIH + 256 + h]);
      const float bh = b2f(g_wsmall[OFF_BHH + 256 + h]);
#pragma unroll
      for (int tt = 0; tt < TM; tt++) {
        racc[tt][0]=br; racc[tt][1]=br; racc[tt][2]=br; racc[tt][3]=br;
        zacc[tt][0]=bz; zacc[tt][1]=bz; zacc[tt][2]=bz; zacc[tt][3]=bz;
        niacc[tt][0]=bn; niacc[tt][1]=bn; niacc[tt][2]=bn; niacc[tt][3]=bn;
        nhacc[tt][0]=bh; nhacc[tt][1]=bh; nhacc[tt][2]=bh; nhacc[tt][3]=bh;
      }
    }
    // r: rows [0,128): gi uses ctx, gh uses x; shared accumulator
#pragma unroll
    for (int kk = 0; kk < 4; kk++) {
      bf16x8 b = load_frag(W_ih + h * D_FEAT + kk * 32 + quad * 8);
#pragma unroll
      for (int tt = 0; tt < TM; tt++)
        racc[tt] = __builtin_amdgcn_mfma_f32_16x16x32_bf16(ac[tt][kk], b, racc[tt], 0, 0, 0);
    }
#pragma unroll
    for (int kk = 0; kk < 4; kk++) {
      bf16x8 b = load_frag(W_hh + h * D_FEAT + kk * 32 + quad * 8);
#pragma unroll
      for (int tt = 0; tt < TM; tt++)
        racc[tt] = __builtin_amdgcn_mfma_f32_16x16x32_bf16(ax[tt][kk], b, racc[tt], 0, 0, 0);
    }
    // z: rows [128,256)
#pragma unroll
    for (int kk = 0; kk < 4; kk++) {
      bf16x8 b = load_frag(W_ih + (128 + h) * D_FEAT + kk * 32 + quad * 8);
#pragma unroll
      for (int tt = 0; tt < TM; tt++)
        zacc[tt] = __builtin_amdgcn_mfma_f32_16x16x32_bf16(ac[tt][kk], b, zacc[tt], 0, 0, 0);
    }
#pragma unroll
    for (int kk = 0; kk < 4; kk++) {
      bf16x8 b = load_frag(W_hh + (128 + h) * D_FEAT + kk * 32 + quad * 8);
#pragma unroll
      for (int tt = 0; tt < TM; tt++)
        zacc[tt] = __builtin_amdgcn_mfma_f32_16x16x32_bf16(ax[tt][kk], b, zacc[tt], 0, 0, 0);
    }
    // n: rows [256,384), separate accs (r gates only gh_n)
#pragma unroll
    for (int kk = 0; kk < 4; kk++) {
      bf16x8 b = load_frag(W_ih + (256 + h) * D_FEAT + kk * 32 + quad * 8);
#pragma unroll
      for (int tt = 0; tt < TM; tt++)
        niacc[tt] = __builtin_amdgcn_mfma_f32_16x16x32_bf16(ac[tt][kk], b, niacc[tt], 0, 0, 0);
    }
#pragma unroll
    for (int kk = 0; kk < 4; kk++) {
      bf16x8 b = load_frag(W_hh + (256 + h) * D_FEAT + kk * 32 + quad * 8);
#pragma unroll
      for (int tt = 0; tt < TM; tt++)
        nhacc[tt] = __builtin_amdgcn_mfma_f32_16x16x32_bf16(ax[tt][kk], b, nhacc[tt], 0, 0, 0);
    }
    // gate math + store for this j (output col h depends only on these accs)
#pragma unroll
    for (int tt = 0; tt < TM; tt++) {
      const int tile = tile0 + tt;
      if (tile >= NTILE) break;
#pragma unroll
      for (int r = 0; r < 4; r++) {
        const int vrow = tile * 16 + quad * 4 + r;
        const float rg = 1.f / (1.f + __expf(-racc[tt][r]));
        const float zg = 1.f / (1.f + __expf(-zacc[tt][r]));
        const float n  = tanhf(niacc[tt][r] + rg * nhacc[tt][r]);
        const float xv = isb ? b2f(g_xbf[vrow * D_FEAT + h]) : xf32[vrow * D_FEAT + h];
        const float hn = (1.f - zg) * n + zg * xv;
        out[vrow * D_FEAT + h] = (hn < 0.f) ? 0.f : hn;  // relu; NaN passes (canary)
      }
    }
  }
}

// ---------------- launch ------------------------------------------------------
extern "C" void kernel_launch(void* const* d_in, const int* in_sizes, int n_in,
                              void* d_out, int out_size, void* d_ws, size_t ws_size,
                              hipStream_t stream)
{
  (void)d_ws; (void)ws_size; (void)out_size;

  // resolve inputs by element count (same-size pairs keep dict order)
  int ix = -1, iWe = -1, ibe = -1, iWp = -1, ibp = -1,
      iWih = -1, iWhh = -1, ibih = -1, ibhh = -1, isrc = -1, idst = -1;
  for (int i = 0; i < n_in; i++) {
    const int s = in_sizes[i];
    if      (s == 6400000) ix = i;
    else if (s == 256)     iWe = i;
    else if (s == 1)       ibe = i;
    else if (s == 16384)   iWp = i;
    else if (s == 128)     ibp = i;
    else if (s == 49152)   { if (iWih < 0) iWih = i; else iWhh = i; }
    else if (s == 384)     { if (ibih < 0) ibih = i; else ibhh = i; }
    else if (s == 800000)  { if (isrc < 0) isrc = i; else idst = i; }
  }
  if (ix < 0 || iWe < 0 || ibe < 0 || iWp < 0 || ibp < 0 || iWih < 0 ||
      iWhh < 0 || ibih < 0 || ibhh < 0 || isrc < 0 || idst < 0) {
    ix = 0; iWe = 1; ibe = 2; iWp = 3; ibp = 4;           // dict-order fallback
    iWih = 5; iWhh = 6; ibih = 7; ibhh = 8; isrc = 9; idst = 10;
  }

  const int* src = (const int*)d_in[isrc];
  const int* dst = (const int*)d_in[idst];
  float* out = (float*)d_out;
  const int mfma_grid = (NTILE + TM - 1) / TM;  // 782

  probe_kernel<<<1, 256, 0, stream>>>((const unsigned int*)d_in[ix]);
  conv_x_kernel<<<V_NODES * D_FEAT / 4 / 256, 256, 0, stream>>>(d_in[ix]);
  conv_small_kernel<<<(SMALL_TOTAL + 255) / 256, 256, 0, stream>>>(
      d_in[iWe], d_in[iWp], d_in[iWih], d_in[iWhh],
      d_in[ibe], d_in[ibp], d_in[ibih], d_in[ibhh]);
  zero_counts_kernel<<<(V_NODES + 255) / 256, 256, 0, stream>>>();
  node_pre_kernel<<<mfma_grid, 64, 0, stream>>>();
  hist_kernel<<<E_EDGES / 256, 256, 0, stream>>>(dst, E_EDGES);
  scan_kernel<<<1, 1024, 0, stream>>>();
  edge_scatter_kernel<<<E_EDGES / 256, 256, 0, stream>>>(src, dst, E_EDGES);
  aggregate_kernel<<<V_NODES, 64, 0, stream>>>();
  gru_kernel<<<mfma_grid, 64, 0, stream>>>((const float*)d_in[ix], out);
}

// Round 8
// 441.321 us; speedup vs baseline: 1.2220x; 1.2220x over previous
//
#include <hip/hip_runtime.h>
#include <hip/hip_bf16.h>

// GNN attention layer. V=50000, E=800000, D=H=128. Inputs f32, OUTPUT f32.
//
// R8: R7's TM=4 regressed (compiler kept VGPR=116 -> rematerialized A-frags;
// TLP fell 4x). Revert to TM=1/wave; hide L2 latency with WAVES:
//  - gru/node_pre: 256-thr blocks, 4 waves, one 16-row tile per wave. Waves
//    share weight fragments via L1 (24 KB/j-iter working set fits 32 KB L1).
//  - hist fused into node_pre launch (independent blocks overlap).
//  - conv_x + zero_counts + conv_small fused into one launch.
//  - aggregate: 4 nodes/block (one per wave), 4x-unrolled gather.
//  - scan: R7 version (sequential partials + one LDS scan).

#define V_NODES 50000
#define E_EDGES 800000
#define D_FEAT  128
#define NTILE   3125          // V/16

typedef short bf16x8 __attribute__((ext_vector_type(8)));  // 8 bf16 in 4 VGPRs
typedef float f32x4  __attribute__((ext_vector_type(4)));
typedef unsigned short u16x4 __attribute__((ext_vector_type(4)));

// small-tensor bf16 pool element offsets
#define OFF_WEDGE 0
#define OFF_WPROJ 256
#define OFF_WIH   16640
#define OFF_WHH   65792
#define OFF_BEDGE 114944
#define OFF_BPROJ 114945
#define OFF_BIH   115073
#define OFF_BHH   115457
#define SMALL_TOTAL 115841
#define CONV_X_BLOCKS   6250   // 1.6M u16x4 / 256
#define ZERO_BLOCKS     196
#define CONV_S_BLOCKS   453
#define NP_BLOCKS       782    // ceil(3125/4)
#define HIST_BLOCKS     3125   // 800000/256

// ---- device-global scratch (~46 MB; immune to ws_size) ----
__device__ int   g_is_bf16;
__device__ float g_pd[V_NODES];
__device__ float g_ps[V_NODES];
__device__ int   g_counts[V_NODES];
__device__ int   g_row_off[V_NODES + 1];
__device__ int   g_cursor[V_NODES];
__device__ int   g_s_src[E_EDGES];
__device__ float g_s_val[E_EDGES];
__device__ __attribute__((aligned(16))) unsigned short g_xbf[V_NODES * D_FEAT];
__device__ __attribute__((aligned(16))) unsigned short g_wsmall[SMALL_TOTAL + 15];
__device__ __attribute__((aligned(16))) unsigned short g_hv[V_NODES * D_FEAT];
__device__ __attribute__((aligned(16))) unsigned short g_ctx[V_NODES * D_FEAT];

static __device__ __forceinline__ float b2f(unsigned short u) {
  union { unsigned int i; float f; } v; v.i = ((unsigned int)u) << 16; return v.f;
}
static __device__ __forceinline__ unsigned short f2b(float f) {
  unsigned int i = __float_as_uint(f);
  unsigned int r = (i + 0x7FFFu + ((i >> 16) & 1u)) >> 16;  // RNE (NaN stays NaN)
  return (unsigned short)r;
}
static __device__ __forceinline__ bf16x8 load_frag(const unsigned short* p) {
  return *reinterpret_cast<const bf16x8*>(p);  // 16B-aligned vector load
}

// ---------------- P: dtype probe on x ----------------------------------------
__global__ void probe_kernel(const unsigned int* __restrict__ x)
{
  __shared__ int cnt;
  if (threadIdx.x == 0) cnt = 0;
  __syncthreads();
  const unsigned int w  = x[threadIdx.x];
  const unsigned int lo = w & 0xFFFFu;
  const unsigned int ex = (lo >> 7) & 0xFFu;
  if (lo != 0u && ex >= 118u && ex <= 132u) atomicAdd(&cnt, 1);
  __syncthreads();
  if (threadIdx.x == 0) g_is_bf16 = (cnt >= 200) ? 1 : 0;
}

// ---------------- C: fused convert-x | zero-counts | convert-smalls ----------
__global__ void conv_fused_kernel(
    const void* __restrict__ x,
    const void* p0, const void* p1, const void* p2, const void* p3,
    const void* p4, const void* p5, const void* p6, const void* p7)
{
  const int b = blockIdx.x;
  if (b < CONV_X_BLOCKS) {
    const int t = b * 256 + threadIdx.x;
    if (g_is_bf16) {
      reinterpret_cast<u16x4*>(g_xbf)[t] = reinterpret_cast<const u16x4*>(x)[t];
    } else {
      const float4 v = reinterpret_cast<const float4*>(x)[t];
      u16x4 o; o.x = f2b(v.x); o.y = f2b(v.y); o.z = f2b(v.z); o.w = f2b(v.w);
      reinterpret_cast<u16x4*>(g_xbf)[t] = o;
    }
  } else if (b < CONV_X_BLOCKS + ZERO_BLOCKS) {
    const int i = (b - CONV_X_BLOCKS) * 256 + threadIdx.x;
    if (i < V_NODES) g_counts[i] = 0;
  } else {
    const int i = (b - CONV_X_BLOCKS - ZERO_BLOCKS) * 256 + threadIdx.x;
    if (i >= SMALL_TOTAL) return;
    const int offs[9] = {OFF_WEDGE, OFF_WPROJ, OFF_WIH, OFF_WHH,
                         OFF_BEDGE, OFF_BPROJ, OFF_BIH, OFF_BHH, SMALL_TOTAL};
    const void* ps[8] = {p0, p1, p2, p3, p4, p5, p6, p7};
    int r = 0;
#pragma unroll
    for (int k = 0; k < 8; k++) if (i >= offs[k]) r = k;
    const int j = i - offs[r];
    g_wsmall[i] = g_is_bf16
        ? reinterpret_cast<const unsigned short*>(ps[r])[j]
        : f2b(reinterpret_cast<const float*>(ps[r])[j]);
  }
}

// ---------------- K1: node_pre (4 waves/block, tile per wave) + hist ----------
__global__ __launch_bounds__(256) void np_hist_kernel(const int* __restrict__ dst)
{
  const int b = blockIdx.x;
  if (b >= NP_BLOCKS) {                      // ---- histogram part ----
    const int e = (b - NP_BLOCKS) * 256 + threadIdx.x;
    if (e < E_EDGES) atomicAdd(&g_counts[dst[e]], 1);
    return;
  }
  // ---- node_pre part: wave w of this block handles tile b*4+w ----
  const int wave = threadIdx.x >> 6;
  const int lane = threadIdx.x & 63;
  const int tile = b * 4 + wave;
  if (tile >= NTILE) return;                 // whole-wave uniform exit, no LDS
  const int col  = lane & 15;
  const int quad = lane >> 4;
  const int arow = tile * 16 + col;
  const unsigned short* W_edge = g_wsmall + OFF_WEDGE;
  const unsigned short* W_proj = g_wsmall + OFF_WPROJ;

  bf16x8 a[4];
#pragma unroll
  for (int kk = 0; kk < 4; kk++)
    a[kk] = load_frag(g_xbf + arow * D_FEAT + kk * 32 + quad * 8);

  f32x4 acc[8];
#pragma unroll
  for (int j = 0; j < 8; j++) { acc[j][0]=0.f; acc[j][1]=0.f; acc[j][2]=0.f; acc[j][3]=0.f; }
  f32x4 acce; acce[0]=0.f; acce[1]=0.f; acce[2]=0.f; acce[3]=0.f;

#pragma unroll
  for (int kk = 0; kk < 4; kk++) {
    bf16x8 be = {0,0,0,0,0,0,0,0};
    if (col < 2)  // n=0 -> w_dst, n=1 -> w_src
      be = load_frag(W_edge + col * D_FEAT + kk * 32 + quad * 8);
    acce = __builtin_amdgcn_mfma_f32_16x16x32_bf16(a[kk], be, acce, 0, 0, 0);
#pragma unroll
    for (int j = 0; j < 8; j++) {
      bf16x8 bw = load_frag(W_proj + (16 * j + col) * D_FEAT + kk * 32 + quad * 8);
      acc[j] = __builtin_amdgcn_mfma_f32_16x16x32_bf16(a[kk], bw, acc[j], 0, 0, 0);
    }
  }

#pragma unroll
  for (int j = 0; j < 8; j++) {
    const int h = 16 * j + col;
    const float bp = b2f(g_wsmall[OFF_BPROJ + h]);
#pragma unroll
    for (int r = 0; r < 4; r++) {
      const int vrow = tile * 16 + quad * 4 + r;
      g_hv[vrow * D_FEAT + h] = f2b(acc[j][r] + bp);
    }
  }
  if (col == 0) {
#pragma unroll
    for (int r = 0; r < 4; r++) g_pd[tile * 16 + quad * 4 + r] = acce[r];
  } else if (col == 1) {
#pragma unroll
    for (int r = 0; r < 4; r++) g_ps[tile * 16 + quad * 4 + r] = acce[r];
  }
}

// ---------------- K3: scan (sequential partials + one LDS scan) ---------------
__global__ __launch_bounds__(1024) void scan_kernel()
{
  __shared__ int lds[1024];
  const int tid = threadIdx.x;
  const int PER = 49;                       // ceil(50000/1024)
  const int base = tid * PER;
  int s = 0;
  for (int k = 0; k < PER; k++) {
    const int idx = base + k;
    if (idx < V_NODES) s += g_counts[idx];
  }
  lds[tid] = s;
  __syncthreads();
  for (int off = 1; off < 1024; off <<= 1) {
    int t = (tid >= off) ? lds[tid - off] : 0;
    __syncthreads();
    lds[tid] += t;
    __syncthreads();
  }
  int run = lds[tid] - s;                   // exclusive prefix of this thread
  for (int k = 0; k < PER; k++) {
    const int idx = base + k;
    if (idx < V_NODES) {
      g_row_off[idx] = run;
      g_cursor[idx]  = run;
      run += g_counts[idx];
    }
  }
  if (tid == 1023) g_row_off[V_NODES] = run;
}

// ---------------- K4: edge scatter (CSR fill + softmax numerator) ------------
__global__ void edge_scatter_kernel(
    const int* __restrict__ src, const int* __restrict__ dst, int E)
{
  int e = blockIdx.x * blockDim.x + threadIdx.x;
  if (e >= E) return;
  const int d = dst[e], sn = src[e];
  float logit = g_pd[d] + g_ps[sn] + b2f(g_wsmall[OFF_BEDGE]);
  logit = (logit >= 0.f) ? logit : 0.01f * logit;           // LeakyReLU(0.01)
  const float w = __expf(logit);                            // no max-sub: cancels
  const int pos = atomicAdd(&g_cursor[d], 1);
  g_s_src[pos] = sn;
  g_s_val[pos] = w;
}

// ---------------- K5: aggregation, 4 nodes/block (one per wave) --------------
__global__ __launch_bounds__(256) void aggregate_kernel()
{
  const int v = blockIdx.x * 4 + (threadIdx.x >> 6);   // grid 12500 -> v < 50000
  const int lane = threadIdx.x & 63;                   // lane: cols 2l, 2l+1
  const int beg = g_row_off[v], end = g_row_off[v + 1];
  float accx = 0.f, accy = 0.f, ssum = 0.f;
  int i = beg;
  for (; i + 4 <= end; i += 4) {       // 4 gathers in flight
    const int   s0 = g_s_src[i],     s1 = g_s_src[i + 1],
                s2 = g_s_src[i + 2], s3 = g_s_src[i + 3];
    const float w0 = g_s_val[i],     w1 = g_s_val[i + 1],
                w2 = g_s_val[i + 2], w3 = g_s_val[i + 3];
    const unsigned int p0 = *reinterpret_cast<const unsigned int*>(g_hv + s0 * D_FEAT + lane * 2);
    const unsigned int p1 = *reinterpret_cast<const unsigned int*>(g_hv + s1 * D_FEAT + lane * 2);
    const unsigned int p2 = *reinterpret_cast<const unsigned int*>(g_hv + s2 * D_FEAT + lane * 2);
    const unsigned int p3 = *reinterpret_cast<const unsigned int*>(g_hv + s3 * D_FEAT + lane * 2);
    ssum += (w0 + w1) + (w2 + w3);
    accx += w0 * b2f((unsigned short)(p0 & 0xFFFFu)) + w1 * b2f((unsigned short)(p1 & 0xFFFFu))
          + w2 * b2f((unsigned short)(p2 & 0xFFFFu)) + w3 * b2f((unsigned short)(p3 & 0xFFFFu));
    accy += w0 * b2f((unsigned short)(p0 >> 16)) + w1 * b2f((unsigned short)(p1 >> 16))
          + w2 * b2f((unsigned short)(p2 >> 16)) + w3 * b2f((unsigned short)(p3 >> 16));
  }
  for (; i < end; i++) {
    const int sn  = g_s_src[i];
    const float w = g_s_val[i];
    ssum += w;
    const unsigned int pair =
        *reinterpret_cast<const unsigned int*>(g_hv + sn * D_FEAT + lane * 2);
    accx += w * b2f((unsigned short)(pair & 0xFFFFu));
    accy += w * b2f((unsigned short)(pair >> 16));
  }
  const float inv = (end > beg) ? (1.0f / ssum) : 0.0f;     // empty segment -> c=0
  float c0 = accx * inv, c1 = accy * inv;
  c0 = (c0 > 0.f) ? c0 : (__expf(c0) - 1.f);                // elu
  c1 = (c1 > 0.f) ? c1 : (__expf(c1) - 1.f);
  const unsigned int outp = ((unsigned int)f2b(c1) << 16) | (unsigned int)f2b(c0);
  *reinterpret_cast<unsigned int*>(g_ctx + v * D_FEAT + lane * 2) = outp;
}

// ---------------- K6: GRUCell + relu (4 waves/block, tile per wave) ----------
__global__ __launch_bounds__(256) void gru_kernel(const float* __restrict__ xf32,
                                                  float* __restrict__ out)
{
  const int wave = threadIdx.x >> 6;
  const int lane = threadIdx.x & 63;
  const int tile = blockIdx.x * 4 + wave;
  if (tile >= NTILE) return;                 // whole-wave uniform exit, no LDS
  const int col  = lane & 15;
  const int quad = lane >> 4;
  const int arow = tile * 16 + col;
  const unsigned short* W_ih = g_wsmall + OFF_WIH;
  const unsigned short* W_hh = g_wsmall + OFF_WHH;
  const int isb = g_is_bf16;

  bf16x8 ax[4], ac[4];
#pragma unroll
  for (int kk = 0; kk < 4; kk++) {
    ax[kk] = load_frag(g_xbf + arow * D_FEAT + kk * 32 + quad * 8);
    ac[kk] = load_frag(g_ctx + arow * D_FEAT + kk * 32 + quad * 8);
  }

#pragma unroll
  for (int j = 0; j < 8; j++) {
    const int h = 16 * j + col;
    const float br = b2f(g_wsmall[OFF_BIH + h])       + b2f(g_wsmall[OFF_BHH + h]);
    const float bz = b2f(g_wsmall[OFF_BIH + 128 + h]) + b2f(g_wsmall[OFF_BHH + 128 + h]);
    const float bn = b2f(g_wsmall[OFF_BIH + 256 + h]);
    const float bh = b2f(g_wsmall[OFF_BHH + 256 + h]);
    f32x4 racc, zacc, niacc, nhacc;
    racc[0]=br; racc[1]=br; racc[2]=br; racc[3]=br;
    zacc[0]=bz; zacc[1]=bz; zacc[2]=bz; zacc[3]=bz;
    niacc[0]=bn; niacc[1]=bn; niacc[2]=bn; niacc[3]=bn;
    nhacc[0]=bh; nhacc[1]=bh; nhacc[2]=bh; nhacc[3]=bh;
#pragma unroll
    for (int kk = 0; kk < 4; kk++) {
      bf16x8 b1 = load_frag(W_ih + h * D_FEAT + kk * 32 + quad * 8);
      bf16x8 b2 = load_frag(W_hh + h * D_FEAT + kk * 32 + quad * 8);
      bf16x8 b3 = load_frag(W_ih + (128 + h) * D_FEAT + kk * 32 + quad * 8);
      bf16x8 b4 = load_frag(W_hh + (128 + h) * D_FEAT + kk * 32 + quad * 8);
      bf16x8 b5 = load_frag(W_ih + (256 + h) * D_FEAT + kk * 32 + quad * 8);
      bf16x8 b6 = load_frag(W_hh + (256 + h) * D_FEAT + kk * 32 + quad * 8);
      racc  = __builtin_amdgcn_mfma_f32_16x16x32_bf16(ac[kk], b1, racc, 0, 0, 0);
      racc  = __builtin_amdgcn_mfma_f32_16x16x32_bf16(ax[kk], b2, racc, 0, 0, 0);
      zacc  = __builtin_amdgcn_mfma_f32_16x16x32_bf16(ac[kk], b3, zacc, 0, 0, 0);
      zacc  = __builtin_amdgcn_mfma_f32_16x16x32_bf16(ax[kk], b4, zacc, 0, 0, 0);
      niacc = __builtin_amdgcn_mfma_f32_16x16x32_bf16(ac[kk], b5, niacc, 0, 0, 0);
      nhacc = __builtin_amdgcn_mfma_f32_16x16x32_bf16(ax[kk], b6, nhacc, 0, 0, 0);
    }
#pragma unroll
    for (int r = 0; r < 4; r++) {
      const int vrow = tile * 16 + quad * 4 + r;
      const float rg = 1.f / (1.f + __expf(-racc[r]));
      const float zg = 1.f / (1.f + __expf(-zacc[r]));
      const float n  = tanhf(niacc[r] + rg * nhacc[r]);
      const float xv = isb ? b2f(g_xbf[vrow * D_FEAT + h]) : xf32[vrow * D_FEAT + h];
      const float hn = (1.f - zg) * n + zg * xv;
      out[vrow * D_FEAT + h] = (hn < 0.f) ? 0.f : hn;  // relu; NaN passes (canary)
    }
  }
}

// ---------------- launch ------------------------------------------------------
extern "C" void kernel_launch(void* const* d_in, const int* in_sizes, int n_in,
                              void* d_out, int out_size, void* d_ws, size_t ws_size,
                              hipStream_t stream)
{
  (void)d_ws; (void)ws_size; (void)out_size;

  // resolve inputs by element count (same-size pairs keep dict order)
  int ix = -1, iWe = -1, ibe = -1, iWp = -1, ibp = -1,
      iWih = -1, iWhh = -1, ibih = -1, ibhh = -1, isrc = -1, idst = -1;
  for (int i = 0; i < n_in; i++) {
    const int s = in_sizes[i];
    if      (s == 6400000) ix = i;
    else if (s == 256)     iWe = i;
    else if (s == 1)       ibe = i;
    else if (s == 16384)   iWp = i;
    else if (s == 128)     ibp = i;
    else if (s == 49152)   { if (iWih < 0) iWih = i; else iWhh = i; }
    else if (s == 384)     { if (ibih < 0) ibih = i; else ibhh = i; }
    else if (s == 800000)  { if (isrc < 0) isrc = i; else idst = i; }
  }
  if (ix < 0 || iWe < 0 || ibe < 0 || iWp < 0 || ibp < 0 || iWih < 0 ||
      iWhh < 0 || ibih < 0 || ibhh < 0 || isrc < 0 || idst < 0) {
    ix = 0; iWe = 1; ibe = 2; iWp = 3; ibp = 4;           // dict-order fallback
    iWih = 5; iWhh = 6; ibih = 7; ibhh = 8; isrc = 9; idst = 10;
  }

  const int* src = (const int*)d_in[isrc];
  const int* dst = (const int*)d_in[idst];
  float* out = (float*)d_out;

  probe_kernel<<<1, 256, 0, stream>>>((const unsigned int*)d_in[ix]);
  conv_fused_kernel<<<CONV_X_BLOCKS + ZERO_BLOCKS + CONV_S_BLOCKS, 256, 0, stream>>>(
      d_in[ix],
      d_in[iWe], d_in[iWp], d_in[iWih], d_in[iWhh],
      d_in[ibe], d_in[ibp], d_in[ibih], d_in[ibhh]);
  np_hist_kernel<<<NP_BLOCKS + HIST_BLOCKS, 256, 0, stream>>>(dst);
  scan_kernel<<<1, 1024, 0, stream>>>();
  edge_scatter_kernel<<<E_EDGES / 256, 256, 0, stream>>>(src, dst, E_EDGES);
  aggregate_kernel<<<V_NODES / 4, 256, 0, stream>>>();
  gru_kernel<<<NP_BLOCKS, 256, 0, stream>>>((const float*)d_in[ix], out);
}

// Round 9
// 335.590 us; speedup vs baseline: 1.6070x; 1.3151x over previous
//
#include <hip/hip_runtime.h>
#include <hip/hip_bf16.h>

// GNN attention layer. V=50000, E=800000, D=H=128. Inputs f32, OUTPUT f32.
//
// R9: R8's single-block scan was the top kernel at 126 us (one CU, uncoalesced
// 49-per-thread walk). Replaced with 3-phase multi-block scan (block-local LDS
// scan -> scan of 196 block totals -> add offsets). Everything else = R8:
//  - gru/node_pre: 256-thr blocks, 4 waves, one 16-row tile per wave (L1 share)
//  - hist fused into node_pre launch; conv_x+zero+conv_small fused
//  - aggregate: 4 nodes/block, 4x-unrolled gather

#define V_NODES 50000
#define E_EDGES 800000
#define D_FEAT  128
#define NTILE   3125          // V/16
#define SCAN_BLOCKS 196       // ceil(50000/256)

typedef short bf16x8 __attribute__((ext_vector_type(8)));  // 8 bf16 in 4 VGPRs
typedef float f32x4  __attribute__((ext_vector_type(4)));
typedef unsigned short u16x4 __attribute__((ext_vector_type(4)));

// small-tensor bf16 pool element offsets
#define OFF_WEDGE 0
#define OFF_WPROJ 256
#define OFF_WIH   16640
#define OFF_WHH   65792
#define OFF_BEDGE 114944
#define OFF_BPROJ 114945
#define OFF_BIH   115073
#define OFF_BHH   115457
#define SMALL_TOTAL 115841
#define CONV_X_BLOCKS   6250   // 1.6M u16x4 / 256
#define ZERO_BLOCKS     196
#define CONV_S_BLOCKS   453
#define NP_BLOCKS       782    // ceil(3125/4)
#define HIST_BLOCKS     3125   // 800000/256

// ---- device-global scratch (~46 MB; immune to ws_size) ----
__device__ int   g_is_bf16;
__device__ float g_pd[V_NODES];
__device__ float g_ps[V_NODES];
__device__ int   g_counts[V_NODES];
__device__ int   g_row_off[V_NODES + 1];
__device__ int   g_cursor[V_NODES];
__device__ int   g_blocksum[SCAN_BLOCKS];
__device__ int   g_blockoff[SCAN_BLOCKS];
__device__ int   g_s_src[E_EDGES];
__device__ float g_s_val[E_EDGES];
__device__ __attribute__((aligned(16))) unsigned short g_xbf[V_NODES * D_FEAT];
__device__ __attribute__((aligned(16))) unsigned short g_wsmall[SMALL_TOTAL + 15];
__device__ __attribute__((aligned(16))) unsigned short g_hv[V_NODES * D_FEAT];
__device__ __attribute__((aligned(16))) unsigned short g_ctx[V_NODES * D_FEAT];

static __device__ __forceinline__ float b2f(unsigned short u) {
  union { unsigned int i; float f; } v; v.i = ((unsigned int)u) << 16; return v.f;
}
static __device__ __forceinline__ unsigned short f2b(float f) {
  unsigned int i = __float_as_uint(f);
  unsigned int r = (i + 0x7FFFu + ((i >> 16) & 1u)) >> 16;  // RNE (NaN stays NaN)
  return (unsigned short)r;
}
static __device__ __forceinline__ bf16x8 load_frag(const unsigned short* p) {
  return *reinterpret_cast<const bf16x8*>(p);  // 16B-aligned vector load
}

// ---------------- P: dtype probe on x ----------------------------------------
__global__ void probe_kernel(const unsigned int* __restrict__ x)
{
  __shared__ int cnt;
  if (threadIdx.x == 0) cnt = 0;
  __syncthreads();
  const unsigned int w  = x[threadIdx.x];
  const unsigned int lo = w & 0xFFFFu;
  const unsigned int ex = (lo >> 7) & 0xFFu;
  if (lo != 0u && ex >= 118u && ex <= 132u) atomicAdd(&cnt, 1);
  __syncthreads();
  if (threadIdx.x == 0) g_is_bf16 = (cnt >= 200) ? 1 : 0;
}

// ---------------- C: fused convert-x | zero-counts | convert-smalls ----------
__global__ void conv_fused_kernel(
    const void* __restrict__ x,
    const void* p0, const void* p1, const void* p2, const void* p3,
    const void* p4, const void* p5, const void* p6, const void* p7)
{
  const int b = blockIdx.x;
  if (b < CONV_X_BLOCKS) {
    const int t = b * 256 + threadIdx.x;
    if (g_is_bf16) {
      reinterpret_cast<u16x4*>(g_xbf)[t] = reinterpret_cast<const u16x4*>(x)[t];
    } else {
      const float4 v = reinterpret_cast<const float4*>(x)[t];
      u16x4 o; o.x = f2b(v.x); o.y = f2b(v.y); o.z = f2b(v.z); o.w = f2b(v.w);
      reinterpret_cast<u16x4*>(g_xbf)[t] = o;
    }
  } else if (b < CONV_X_BLOCKS + ZERO_BLOCKS) {
    const int i = (b - CONV_X_BLOCKS) * 256 + threadIdx.x;
    if (i < V_NODES) g_counts[i] = 0;
  } else {
    const int i = (b - CONV_X_BLOCKS - ZERO_BLOCKS) * 256 + threadIdx.x;
    if (i >= SMALL_TOTAL) return;
    const int offs[9] = {OFF_WEDGE, OFF_WPROJ, OFF_WIH, OFF_WHH,
                         OFF_BEDGE, OFF_BPROJ, OFF_BIH, OFF_BHH, SMALL_TOTAL};
    const void* ps[8] = {p0, p1, p2, p3, p4, p5, p6, p7};
    int r = 0;
#pragma unroll
    for (int k = 0; k < 8; k++) if (i >= offs[k]) r = k;
    const int j = i - offs[r];
    g_wsmall[i] = g_is_bf16
        ? reinterpret_cast<const unsigned short*>(ps[r])[j]
        : f2b(reinterpret_cast<const float*>(ps[r])[j]);
  }
}

// ---------------- K1: node_pre (4 waves/block, tile per wave) + hist ----------
__global__ __launch_bounds__(256) void np_hist_kernel(const int* __restrict__ dst)
{
  const int b = blockIdx.x;
  if (b >= NP_BLOCKS) {                      // ---- histogram part ----
    const int e = (b - NP_BLOCKS) * 256 + threadIdx.x;
    if (e < E_EDGES) atomicAdd(&g_counts[dst[e]], 1);
    return;
  }
  // ---- node_pre part: wave w of this block handles tile b*4+w ----
  const int wave = threadIdx.x >> 6;
  const int lane = threadIdx.x & 63;
  const int tile = b * 4 + wave;
  if (tile >= NTILE) return;                 // whole-wave uniform exit, no LDS
  const int col  = lane & 15;
  const int quad = lane >> 4;
  const int arow = tile * 16 + col;
  const unsigned short* W_edge = g_wsmall + OFF_WEDGE;
  const unsigned short* W_proj = g_wsmall + OFF_WPROJ;

  bf16x8 a[4];
#pragma unroll
  for (int kk = 0; kk < 4; kk++)
    a[kk] = load_frag(g_xbf + arow * D_FEAT + kk * 32 + quad * 8);

  f32x4 acc[8];
#pragma unroll
  for (int j = 0; j < 8; j++) { acc[j][0]=0.f; acc[j][1]=0.f; acc[j][2]=0.f; acc[j][3]=0.f; }
  f32x4 acce; acce[0]=0.f; acce[1]=0.f; acce[2]=0.f; acce[3]=0.f;

#pragma unroll
  for (int kk = 0; kk < 4; kk++) {
    bf16x8 be = {0,0,0,0,0,0,0,0};
    if (col < 2)  // n=0 -> w_dst, n=1 -> w_src
      be = load_frag(W_edge + col * D_FEAT + kk * 32 + quad * 8);
    acce = __builtin_amdgcn_mfma_f32_16x16x32_bf16(a[kk], be, acce, 0, 0, 0);
#pragma unroll
    for (int j = 0; j < 8; j++) {
      bf16x8 bw = load_frag(W_proj + (16 * j + col) * D_FEAT + kk * 32 + quad * 8);
      acc[j] = __builtin_amdgcn_mfma_f32_16x16x32_bf16(a[kk], bw, acc[j], 0, 0, 0);
    }
  }

#pragma unroll
  for (int j = 0; j < 8; j++) {
    const int h = 16 * j + col;
    const float bp = b2f(g_wsmall[OFF_BPROJ + h]);
#pragma unroll
    for (int r = 0; r < 4; r++) {
      const int vrow = tile * 16 + quad * 4 + r;
      g_hv[vrow * D_FEAT + h] = f2b(acc[j][r] + bp);
    }
  }
  if (col == 0) {
#pragma unroll
    for (int r = 0; r < 4; r++) g_pd[tile * 16 + quad * 4 + r] = acce[r];
  } else if (col == 1) {
#pragma unroll
    for (int r = 0; r < 4; r++) g_ps[tile * 16 + quad * 4 + r] = acce[r];
  }
}

// ---------------- K3a: block-local exclusive scan ----------------------------
__global__ __launch_bounds__(256) void scan_a_kernel()
{
  __shared__ int lds[256];
  const int b = blockIdx.x, t = threadIdx.x;
  const int idx = b * 256 + t;
  const int v = (idx < V_NODES) ? g_counts[idx] : 0;
  lds[t] = v;
  __syncthreads();
  for (int off = 1; off < 256; off <<= 1) {
    int tmp = (t >= off) ? lds[t - off] : 0;
    __syncthreads();
    lds[t] += tmp;
    __syncthreads();
  }
  if (idx < V_NODES) g_row_off[idx] = lds[t] - v;   // local exclusive prefix
  if (t == 255) g_blocksum[b] = lds[255];
}

// ---------------- K3b: scan the 196 block totals (1 small block) --------------
__global__ __launch_bounds__(256) void scan_b_kernel()
{
  __shared__ int lds[256];
  const int t = threadIdx.x;
  const int v = (t < SCAN_BLOCKS) ? g_blocksum[t] : 0;
  lds[t] = v;
  __syncthreads();
  for (int off = 1; off < 256; off <<= 1) {
    int tmp = (t >= off) ? lds[t - off] : 0;
    __syncthreads();
    lds[t] += tmp;
    __syncthreads();
  }
  if (t < SCAN_BLOCKS) g_blockoff[t] = lds[t] - v;
  if (t == 255) g_row_off[V_NODES] = lds[255];      // total = E
}

// ---------------- K3c: add block offsets, init cursor -------------------------
__global__ __launch_bounds__(256) void scan_c_kernel()
{
  const int b = blockIdx.x, t = threadIdx.x;
  const int idx = b * 256 + t;
  if (idx >= V_NODES) return;
  const int r = g_row_off[idx] + g_blockoff[b];
  g_row_off[idx] = r;
  g_cursor[idx]  = r;
}

// ---------------- K4: edge scatter (CSR fill + softmax numerator) ------------
__global__ void edge_scatter_kernel(
    const int* __restrict__ src, const int* __restrict__ dst, int E)
{
  int e = blockIdx.x * blockDim.x + threadIdx.x;
  if (e >= E) return;
  const int d = dst[e], sn = src[e];
  float logit = g_pd[d] + g_ps[sn] + b2f(g_wsmall[OFF_BEDGE]);
  logit = (logit >= 0.f) ? logit : 0.01f * logit;           // LeakyReLU(0.01)
  const float w = __expf(logit);                            // no max-sub: cancels
  const int pos = atomicAdd(&g_cursor[d], 1);
  g_s_src[pos] = sn;
  g_s_val[pos] = w;
}

// ---------------- K5: aggregation, 4 nodes/block (one per wave) --------------
__global__ __launch_bounds__(256) void aggregate_kernel()
{
  const int v = blockIdx.x * 4 + (threadIdx.x >> 6);   // grid 12500 -> v < 50000
  const int lane = threadIdx.x & 63;                   // lane: cols 2l, 2l+1
  const int beg = g_row_off[v], end = g_row_off[v + 1];
  float accx = 0.f, accy = 0.f, ssum = 0.f;
  int i = beg;
  for (; i + 4 <= end; i += 4) {       // 4 gathers in flight
    const int   s0 = g_s_src[i],     s1 = g_s_src[i + 1],
                s2 = g_s_src[i + 2], s3 = g_s_src[i + 3];
    const float w0 = g_s_val[i],     w1 = g_s_val[i + 1],
                w2 = g_s_val[i + 2], w3 = g_s_val[i + 3];
    const unsigned int p0 = *reinterpret_cast<const unsigned int*>(g_hv + s0 * D_FEAT + lane * 2);
    const unsigned int p1 = *reinterpret_cast<const unsigned int*>(g_hv + s1 * D_FEAT + lane * 2);
    const unsigned int p2 = *reinterpret_cast<const unsigned int*>(g_hv + s2 * D_FEAT + lane * 2);
    const unsigned int p3 = *reinterpret_cast<const unsigned int*>(g_hv + s3 * D_FEAT + lane * 2);
    ssum += (w0 + w1) + (w2 + w3);
    accx += w0 * b2f((unsigned short)(p0 & 0xFFFFu)) + w1 * b2f((unsigned short)(p1 & 0xFFFFu))
          + w2 * b2f((unsigned short)(p2 & 0xFFFFu)) + w3 * b2f((unsigned short)(p3 & 0xFFFFu));
    accy += w0 * b2f((unsigned short)(p0 >> 16)) + w1 * b2f((unsigned short)(p1 >> 16))
          + w2 * b2f((unsigned short)(p2 >> 16)) + w3 * b2f((unsigned short)(p3 >> 16));
  }
  for (; i < end; i++) {
    const int sn  = g_s_src[i];
    const float w = g_s_val[i];
    ssum += w;
    const unsigned int pair =
        *reinterpret_cast<const unsigned int*>(g_hv + sn * D_FEAT + lane * 2);
    accx += w * b2f((unsigned short)(pair & 0xFFFFu));
    accy += w * b2f((unsigned short)(pair >> 16));
  }
  const float inv = (end > beg) ? (1.0f / ssum) : 0.0f;     // empty segment -> c=0
  float c0 = accx * inv, c1 = accy * inv;
  c0 = (c0 > 0.f) ? c0 : (__expf(c0) - 1.f);                // elu
  c1 = (c1 > 0.f) ? c1 : (__expf(c1) - 1.f);
  const unsigned int outp = ((unsigned int)f2b(c1) << 16) | (unsigned int)f2b(c0);
  *reinterpret_cast<unsigned int*>(g_ctx + v * D_FEAT + lane * 2) = outp;
}

// ---------------- K6: GRUCell + relu (4 waves/block, tile per wave) ----------
__global__ __launch_bounds__(256) void gru_kernel(const float* __restrict__ xf32,
                                                  float* __restrict__ out)
{
  const int wave = threadIdx.x >> 6;
  const int lane = threadIdx.x & 63;
  const int tile = blockIdx.x * 4 + wave;
  if (tile >= NTILE) return;                 // whole-wave uniform exit, no LDS
  const int col  = lane & 15;
  const int quad = lane >> 4;
  const int arow = tile * 16 + col;
  const unsigned short* W_ih = g_wsmall + OFF_WIH;
  const unsigned short* W_hh = g_wsmall + OFF_WHH;
  const int isb = g_is_bf16;

  bf16x8 ax[4], ac[4];
#pragma unroll
  for (int kk = 0; kk < 4; kk++) {
    ax[kk] = load_frag(g_xbf + arow * D_FEAT + kk * 32 + quad * 8);
    ac[kk] = load_frag(g_ctx + arow * D_FEAT + kk * 32 + quad * 8);
  }

#pragma unroll
  for (int j = 0; j < 8; j++) {
    const int h = 16 * j + col;
    const float br = b2f(g_wsmall[OFF_BIH + h])       + b2f(g_wsmall[OFF_BHH + h]);
    const float bz = b2f(g_wsmall[OFF_BIH + 128 + h]) + b2f(g_wsmall[OFF_BHH + 128 + h]);
    const float bn = b2f(g_wsmall[OFF_BIH + 256 + h]);
    const float bh = b2f(g_wsmall[OFF_BHH + 256 + h]);
    f32x4 racc, zacc, niacc, nhacc;
    racc[0]=br; racc[1]=br; racc[2]=br; racc[3]=br;
    zacc[0]=bz; zacc[1]=bz; zacc[2]=bz; zacc[3]=bz;
    niacc[0]=bn; niacc[1]=bn; niacc[2]=bn; niacc[3]=bn;
    nhacc[0]=bh; nhacc[1]=bh; nhacc[2]=bh; nhacc[3]=bh;
#pragma unroll
    for (int kk = 0; kk < 4; kk++) {
      bf16x8 b1 = load_frag(W_ih + h * D_FEAT + kk * 32 + quad * 8);
      bf16x8 b2 = load_frag(W_hh + h * D_FEAT + kk * 32 + quad * 8);
      bf16x8 b3 = load_frag(W_ih + (128 + h) * D_FEAT + kk * 32 + quad * 8);
      bf16x8 b4 = load_frag(W_hh + (128 + h) * D_FEAT + kk * 32 + quad * 8);
      bf16x8 b5 = load_frag(W_ih + (256 + h) * D_FEAT + kk * 32 + quad * 8);
      bf16x8 b6 = load_frag(W_hh + (256 + h) * D_FEAT + kk * 32 + quad * 8);
      racc  = __builtin_amdgcn_mfma_f32_16x16x32_bf16(ac[kk], b1, racc, 0, 0, 0);
      racc  = __builtin_amdgcn_mfma_f32_16x16x32_bf16(ax[kk], b2, racc, 0, 0, 0);
      zacc  = __builtin_amdgcn_mfma_f32_16x16x32_bf16(ac[kk], b3, zacc, 0, 0, 0);
      zacc  = __builtin_amdgcn_mfma_f32_16x16x32_bf16(ax[kk], b4, zacc, 0, 0, 0);
      niacc = __builtin_amdgcn_mfma_f32_16x16x32_bf16(ac[kk], b5, niacc, 0, 0, 0);
      nhacc = __builtin_amdgcn_mfma_f32_16x16x32_bf16(ax[kk], b6, nhacc, 0, 0, 0);
    }
#pragma unroll
    for (int r = 0; r < 4; r++) {
      const int vrow = tile * 16 + quad * 4 + r;
      const float rg = 1.f / (1.f + __expf(-racc[r]));
      const float zg = 1.f / (1.f + __expf(-zacc[r]));
      const float n  = tanhf(niacc[r] + rg * nhacc[r]);
      const float xv = isb ? b2f(g_xbf[vrow * D_FEAT + h]) : xf32[vrow * D_FEAT + h];
      const float hn = (1.f - zg) * n + zg * xv;
      out[vrow * D_FEAT + h] = (hn < 0.f) ? 0.f : hn;  // relu; NaN passes (canary)
    }
  }
}

// ---------------- launch ------------------------------------------------------
extern "C" void kernel_launch(void* const* d_in, const int* in_sizes, int n_in,
                              void* d_out, int out_size, void* d_ws, size_t ws_size,
                              hipStream_t stream)
{
  (void)d_ws; (void)ws_size; (void)out_size;

  // resolve inputs by element count (same-size pairs keep dict order)
  int ix = -1, iWe = -1, ibe = -1, iWp = -1, ibp = -1,
      iWih = -1, iWhh = -1, ibih = -1, ibhh = -1, isrc = -1, idst = -1;
  for (int i = 0; i < n_in; i++) {
    const int s = in_sizes[i];
    if      (s == 6400000) ix = i;
    else if (s == 256)     iWe = i;
    else if (s == 1)       ibe = i;
    else if (s == 16384)   iWp = i;
    else if (s == 128)     ibp = i;
    else if (s == 49152)   { if (iWih < 0) iWih = i; else iWhh = i; }
    else if (s == 384)     { if (ibih < 0) ibih = i; else ibhh = i; }
    else if (s == 800000)  { if (isrc < 0) isrc = i; else idst = i; }
  }
  if (ix < 0 || iWe < 0 || ibe < 0 || iWp < 0 || ibp < 0 || iWih < 0 ||
      iWhh < 0 || ibih < 0 || ibhh < 0 || isrc < 0 || idst < 0) {
    ix = 0; iWe = 1; ibe = 2; iWp = 3; ibp = 4;           // dict-order fallback
    iWih = 5; iWhh = 6; ibih = 7; ibhh = 8; isrc = 9; idst = 10;
  }

  const int* src = (const int*)d_in[isrc];
  const int* dst = (const int*)d_in[idst];
  float* out = (float*)d_out;

  probe_kernel<<<1, 256, 0, stream>>>((const unsigned int*)d_in[ix]);
  conv_fused_kernel<<<CONV_X_BLOCKS + ZERO_BLOCKS + CONV_S_BLOCKS, 256, 0, stream>>>(
      d_in[ix],
      d_in[iWe], d_in[iWp], d_in[iWih], d_in[iWhh],
      d_in[ibe], d_in[ibp], d_in[ibih], d_in[ibhh]);
  np_hist_kernel<<<NP_BLOCKS + HIST_BLOCKS, 256, 0, stream>>>(dst);
  scan_a_kernel<<<SCAN_BLOCKS, 256, 0, stream>>>();
  scan_b_kernel<<<1, 256, 0, stream>>>();
  scan_c_kernel<<<SCAN_BLOCKS, 256, 0, stream>>>();
  edge_scatter_kernel<<<E_EDGES / 256, 256, 0, stream>>>(src, dst, E_EDGES);
  aggregate_kernel<<<V_NODES / 4, 256, 0, stream>>>();
  gru_kernel<<<NP_BLOCKS, 256, 0, stream>>>((const float*)d_in[ix], out);
}

// Round 10
// 284.590 us; speedup vs baseline: 1.8950x; 1.1792x over previous
//
#include <hip/hip_runtime.h>
#include <hip/hip_bf16.h>

// GNN attention layer. V=50000, E=800000, D=H=128. Inputs f32, OUTPUT f32.
//
// R10: gru/node_pre rebuilt as WEIGHT-STATIONARY: each wave owns a 16-column
// gate group, holds its 24 (gru) / 4-8 (node_pre) B-fragments in registers
// (launch_bounds(256,2) lifts the VGPR cap; R9's VGPR=60 was the latency
// culprit), and streams 5 node-tiles with 8 independent A-loads per tile.
// Weight re-reads (600 MB) eliminated; A-traffic 200 MB. Rest = R9:
// 3-phase scan, fused conv, hist fused into np launch, 4x-unrolled aggregate.

#define V_NODES 50000
#define E_EDGES 800000
#define D_FEAT  128
#define NTILE   3125          // V/16
#define SCAN_BLOCKS 196       // ceil(50000/256)
#define GCHUNK  5             // tiles per wave-task (625 chunks x 8 cg = 5000 waves)
#define WS_BLOCKS 1250        // 5000 waves / 4 per block

typedef short bf16x8 __attribute__((ext_vector_type(8)));  // 8 bf16 in 4 VGPRs
typedef float f32x4  __attribute__((ext_vector_type(4)));
typedef unsigned short u16x4 __attribute__((ext_vector_type(4)));

// small-tensor bf16 pool element offsets
#define OFF_WEDGE 0
#define OFF_WPROJ 256
#define OFF_WIH   16640
#define OFF_WHH   65792
#define OFF_BEDGE 114944
#define OFF_BPROJ 114945
#define OFF_BIH   115073
#define OFF_BHH   115457
#define SMALL_TOTAL 115841
#define CONV_X_BLOCKS   6250   // 1.6M u16x4 / 256
#define ZERO_BLOCKS     196
#define CONV_S_BLOCKS   453
#define HIST_BLOCKS     3125   // 800000/256

// ---- device-global scratch (~46 MB; immune to ws_size) ----
__device__ int   g_is_bf16;
__device__ float g_pd[V_NODES];
__device__ float g_ps[V_NODES];
__device__ int   g_counts[V_NODES];
__device__ int   g_row_off[V_NODES + 1];
__device__ int   g_cursor[V_NODES];
__device__ int   g_blocksum[SCAN_BLOCKS];
__device__ int   g_blockoff[SCAN_BLOCKS];
__device__ int   g_s_src[E_EDGES];
__device__ float g_s_val[E_EDGES];
__device__ __attribute__((aligned(16))) unsigned short g_xbf[V_NODES * D_FEAT];
__device__ __attribute__((aligned(16))) unsigned short g_wsmall[SMALL_TOTAL + 15];
__device__ __attribute__((aligned(16))) unsigned short g_hv[V_NODES * D_FEAT];
__device__ __attribute__((aligned(16))) unsigned short g_ctx[V_NODES * D_FEAT];

static __device__ __forceinline__ float b2f(unsigned short u) {
  union { unsigned int i; float f; } v; v.i = ((unsigned int)u) << 16; return v.f;
}
static __device__ __forceinline__ unsigned short f2b(float f) {
  unsigned int i = __float_as_uint(f);
  unsigned int r = (i + 0x7FFFu + ((i >> 16) & 1u)) >> 16;  // RNE (NaN stays NaN)
  return (unsigned short)r;
}
static __device__ __forceinline__ bf16x8 load_frag(const unsigned short* p) {
  return *reinterpret_cast<const bf16x8*>(p);  // 16B-aligned vector load
}

// ---------------- P: dtype probe on x ----------------------------------------
__global__ void probe_kernel(const unsigned int* __restrict__ x)
{
  __shared__ int cnt;
  if (threadIdx.x == 0) cnt = 0;
  __syncthreads();
  const unsigned int w  = x[threadIdx.x];
  const unsigned int lo = w & 0xFFFFu;
  const unsigned int ex = (lo >> 7) & 0xFFu;
  if (lo != 0u && ex >= 118u && ex <= 132u) atomicAdd(&cnt, 1);
  __syncthreads();
  if (threadIdx.x == 0) g_is_bf16 = (cnt >= 200) ? 1 : 0;
}

// ---------------- C: fused convert-x | zero-counts | convert-smalls ----------
__global__ void conv_fused_kernel(
    const void* __restrict__ x,
    const void* p0, const void* p1, const void* p2, const void* p3,
    const void* p4, const void* p5, const void* p6, const void* p7)
{
  const int b = blockIdx.x;
  if (b < CONV_X_BLOCKS) {
    const int t = b * 256 + threadIdx.x;
    if (g_is_bf16) {
      reinterpret_cast<u16x4*>(g_xbf)[t] = reinterpret_cast<const u16x4*>(x)[t];
    } else {
      const float4 v = reinterpret_cast<const float4*>(x)[t];
      u16x4 o; o.x = f2b(v.x); o.y = f2b(v.y); o.z = f2b(v.z); o.w = f2b(v.w);
      reinterpret_cast<u16x4*>(g_xbf)[t] = o;
    }
  } else if (b < CONV_X_BLOCKS + ZERO_BLOCKS) {
    const int i = (b - CONV_X_BLOCKS) * 256 + threadIdx.x;
    if (i < V_NODES) g_counts[i] = 0;
  } else {
    const int i = (b - CONV_X_BLOCKS - ZERO_BLOCKS) * 256 + threadIdx.x;
    if (i >= SMALL_TOTAL) return;
    const int offs[9] = {OFF_WEDGE, OFF_WPROJ, OFF_WIH, OFF_WHH,
                         OFF_BEDGE, OFF_BPROJ, OFF_BIH, OFF_BHH, SMALL_TOTAL};
    const void* ps[8] = {p0, p1, p2, p3, p4, p5, p6, p7};
    int r = 0;
#pragma unroll
    for (int k = 0; k < 8; k++) if (i >= offs[k]) r = k;
    const int j = i - offs[r];
    g_wsmall[i] = g_is_bf16
        ? reinterpret_cast<const unsigned short*>(ps[r])[j]
        : f2b(reinterpret_cast<const float*>(ps[r])[j]);
  }
}

// ---------------- K1: node_pre weight-stationary + hist ----------------------
__global__ __launch_bounds__(256, 2) void np_hist_kernel(const int* __restrict__ dst)
{
  const int b = blockIdx.x;
  if (b >= WS_BLOCKS) {                      // ---- histogram part ----
    const int e = (b - WS_BLOCKS) * 256 + threadIdx.x;
    if (e < E_EDGES) atomicAdd(&g_counts[dst[e]], 1);
    return;
  }
  // ---- node_pre: wave-task g -> col-group cg, tile chunk ----
  const int g     = b * 4 + (threadIdx.x >> 6);
  const int lane  = threadIdx.x & 63;
  const int cg    = g & 7;
  const int chunk = g >> 3;                  // [0, 625)
  const int col   = lane & 15;
  const int quad  = lane >> 4;
  const int h     = 16 * cg + col;

  // resident B fragments: W_proj rows [16cg, 16cg+16)
  bf16x8 bw[4];
#pragma unroll
  for (int kk = 0; kk < 4; kk++)
    bw[kk] = load_frag(g_wsmall + OFF_WPROJ + h * D_FEAT + kk * 32 + quad * 8);
  // cg 0 also owns the edge projections (cols 0/1 of W_edge)
  bf16x8 be[4];
#pragma unroll
  for (int kk = 0; kk < 4; kk++) { be[kk] = bf16x8{0,0,0,0,0,0,0,0}; }
  if (cg == 0 && col < 2) {
#pragma unroll
    for (int kk = 0; kk < 4; kk++)
      be[kk] = load_frag(g_wsmall + OFF_WEDGE + col * D_FEAT + kk * 32 + quad * 8);
  }
  const float bp = b2f(g_wsmall[OFF_BPROJ + h]);

  const int t0 = chunk * GCHUNK;
  for (int t = t0; t < t0 + GCHUNK; t++) {
    const int arow = t * 16 + col;
    bf16x8 a[4];
#pragma unroll
    for (int kk = 0; kk < 4; kk++)
      a[kk] = load_frag(g_xbf + arow * D_FEAT + kk * 32 + quad * 8);
    f32x4 acc; acc[0]=0.f; acc[1]=0.f; acc[2]=0.f; acc[3]=0.f;
#pragma unroll
    for (int kk = 0; kk < 4; kk++)
      acc = __builtin_amdgcn_mfma_f32_16x16x32_bf16(a[kk], bw[kk], acc, 0, 0, 0);
#pragma unroll
    for (int r = 0; r < 4; r++)
      g_hv[(t * 16 + quad * 4 + r) * D_FEAT + h] = f2b(acc[r] + bp);
    if (cg == 0) {
      f32x4 acce; acce[0]=0.f; acce[1]=0.f; acce[2]=0.f; acce[3]=0.f;
#pragma unroll
      for (int kk = 0; kk < 4; kk++)
        acce = __builtin_amdgcn_mfma_f32_16x16x32_bf16(a[kk], be[kk], acce, 0, 0, 0);
      if (col == 0) {
#pragma unroll
        for (int r = 0; r < 4; r++) g_pd[t * 16 + quad * 4 + r] = acce[r];
      } else if (col == 1) {
#pragma unroll
        for (int r = 0; r < 4; r++) g_ps[t * 16 + quad * 4 + r] = acce[r];
      }
    }
  }
}

// ---------------- K3a: block-local exclusive scan ----------------------------
__global__ __launch_bounds__(256) void scan_a_kernel()
{
  __shared__ int lds[256];
  const int b = blockIdx.x, t = threadIdx.x;
  const int idx = b * 256 + t;
  const int v = (idx < V_NODES) ? g_counts[idx] : 0;
  lds[t] = v;
  __syncthreads();
  for (int off = 1; off < 256; off <<= 1) {
    int tmp = (t >= off) ? lds[t - off] : 0;
    __syncthreads();
    lds[t] += tmp;
    __syncthreads();
  }
  if (idx < V_NODES) g_row_off[idx] = lds[t] - v;   // local exclusive prefix
  if (t == 255) g_blocksum[b] = lds[255];
}

// ---------------- K3b: scan the 196 block totals (1 small block) --------------
__global__ __launch_bounds__(256) void scan_b_kernel()
{
  __shared__ int lds[256];
  const int t = threadIdx.x;
  const int v = (t < SCAN_BLOCKS) ? g_blocksum[t] : 0;
  lds[t] = v;
  __syncthreads();
  for (int off = 1; off < 256; off <<= 1) {
    int tmp = (t >= off) ? lds[t - off] : 0;
    __syncthreads();
    lds[t] += tmp;
    __syncthreads();
  }
  if (t < SCAN_BLOCKS) g_blockoff[t] = lds[t] - v;
  if (t == 255) g_row_off[V_NODES] = lds[255];      // total = E
}

// ---------------- K3c: add block offsets, init cursor -------------------------
__global__ __launch_bounds__(256) void scan_c_kernel()
{
  const int b = blockIdx.x, t = threadIdx.x;
  const int idx = b * 256 + t;
  if (idx >= V_NODES) return;
  const int r = g_row_off[idx] + g_blockoff[b];
  g_row_off[idx] = r;
  g_cursor[idx]  = r;
}

// ---------------- K4: edge scatter (CSR fill + softmax numerator) ------------
__global__ void edge_scatter_kernel(
    const int* __restrict__ src, const int* __restrict__ dst, int E)
{
  int e = blockIdx.x * blockDim.x + threadIdx.x;
  if (e >= E) return;
  const int d = dst[e], sn = src[e];
  float logit = g_pd[d] + g_ps[sn] + b2f(g_wsmall[OFF_BEDGE]);
  logit = (logit >= 0.f) ? logit : 0.01f * logit;           // LeakyReLU(0.01)
  const float w = __expf(logit);                            // no max-sub: cancels
  const int pos = atomicAdd(&g_cursor[d], 1);
  g_s_src[pos] = sn;
  g_s_val[pos] = w;
}

// ---------------- K5: aggregation, 4 nodes/block (one per wave) --------------
__global__ __launch_bounds__(256) void aggregate_kernel()
{
  const int v = blockIdx.x * 4 + (threadIdx.x >> 6);   // grid 12500 -> v < 50000
  const int lane = threadIdx.x & 63;                   // lane: cols 2l, 2l+1
  const int beg = g_row_off[v], end = g_row_off[v + 1];
  float accx = 0.f, accy = 0.f, ssum = 0.f;
  int i = beg;
  for (; i + 4 <= end; i += 4) {       // 4 gathers in flight
    const int   s0 = g_s_src[i],     s1 = g_s_src[i + 1],
                s2 = g_s_src[i + 2], s3 = g_s_src[i + 3];
    const float w0 = g_s_val[i],     w1 = g_s_val[i + 1],
                w2 = g_s_val[i + 2], w3 = g_s_val[i + 3];
    const unsigned int p0 = *reinterpret_cast<const unsigned int*>(g_hv + s0 * D_FEAT + lane * 2);
    const unsigned int p1 = *reinterpret_cast<const unsigned int*>(g_hv + s1 * D_FEAT + lane * 2);
    const unsigned int p2 = *reinterpret_cast<const unsigned int*>(g_hv + s2 * D_FEAT + lane * 2);
    const unsigned int p3 = *reinterpret_cast<const unsigned int*>(g_hv + s3 * D_FEAT + lane * 2);
    ssum += (w0 + w1) + (w2 + w3);
    accx += w0 * b2f((unsigned short)(p0 & 0xFFFFu)) + w1 * b2f((unsigned short)(p1 & 0xFFFFu))
          + w2 * b2f((unsigned short)(p2 & 0xFFFFu)) + w3 * b2f((unsigned short)(p3 & 0xFFFFu));
    accy += w0 * b2f((unsigned short)(p0 >> 16)) + w1 * b2f((unsigned short)(p1 >> 16))
          + w2 * b2f((unsigned short)(p2 >> 16)) + w3 * b2f((unsigned short)(p3 >> 16));
  }
  for (; i < end; i++) {
    const int sn  = g_s_src[i];
    const float w = g_s_val[i];
    ssum += w;
    const unsigned int pair =
        *reinterpret_cast<const unsigned int*>(g_hv + sn * D_FEAT + lane * 2);
    accx += w * b2f((unsigned short)(pair & 0xFFFFu));
    accy += w * b2f((unsigned short)(pair >> 16));
  }
  const float inv = (end > beg) ? (1.0f / ssum) : 0.0f;     // empty segment -> c=0
  float c0 = accx * inv, c1 = accy * inv;
  c0 = (c0 > 0.f) ? c0 : (__expf(c0) - 1.f);                // elu
  c1 = (c1 > 0.f) ? c1 : (__expf(c1) - 1.f);
  const unsigned int outp = ((unsigned int)f2b(c1) << 16) | (unsigned int)f2b(c0);
  *reinterpret_cast<unsigned int*>(g_ctx + v * D_FEAT + lane * 2) = outp;
}

// ---------------- K6: GRU weight-stationary (cg per wave, stream tiles) -------
__global__ __launch_bounds__(256, 2) void gru_kernel(const float* __restrict__ xf32,
                                                     float* __restrict__ out)
{
  const int g     = blockIdx.x * 4 + (threadIdx.x >> 6);
  const int lane  = threadIdx.x & 63;
  const int cg    = g & 7;
  const int chunk = g >> 3;                  // [0, 625)
  const int col   = lane & 15;
  const int quad  = lane >> 4;
  const int h     = 16 * cg + col;
  const unsigned short* W_ih = g_wsmall + OFF_WIH;
  const unsigned short* W_hh = g_wsmall + OFF_WHH;
  const int isb = g_is_bf16;

  // per-wave constant biases for columns h
  const float br  = b2f(g_wsmall[OFF_BIH + h])       + b2f(g_wsmall[OFF_BHH + h]);
  const float bz  = b2f(g_wsmall[OFF_BIH + 128 + h]) + b2f(g_wsmall[OFF_BHH + 128 + h]);
  const float bn  = b2f(g_wsmall[OFF_BIH + 256 + h]);
  const float bh_ = b2f(g_wsmall[OFF_BHH + 256 + h]);

  // resident B fragments: 24 frags = 96 VGPRs (launch_bounds(256,2) allows it)
  bf16x8 bIHr[4], bHHr[4], bIHz[4], bHHz[4], bIHn[4], bHHn[4];
#pragma unroll
  for (int kk = 0; kk < 4; kk++) {
    const int ko = kk * 32 + quad * 8;
    bIHr[kk] = load_frag(W_ih + h * D_FEAT + ko);
    bHHr[kk] = load_frag(W_hh + h * D_FEAT + ko);
    bIHz[kk] = load_frag(W_ih + (128 + h) * D_FEAT + ko);
    bHHz[kk] = load_frag(W_hh + (128 + h) * D_FEAT + ko);
    bIHn[kk] = load_frag(W_ih + (256 + h) * D_FEAT + ko);
    bHHn[kk] = load_frag(W_hh + (256 + h) * D_FEAT + ko);
  }

  const int t0 = chunk * GCHUNK;
  for (int t = t0; t < t0 + GCHUNK; t++) {
    const int arow = t * 16 + col;
    bf16x8 ax[4], ac[4];
#pragma unroll
    for (int kk = 0; kk < 4; kk++) {
      ax[kk] = load_frag(g_xbf + arow * D_FEAT + kk * 32 + quad * 8);
      ac[kk] = load_frag(g_ctx + arow * D_FEAT + kk * 32 + quad * 8);
    }
    f32x4 racc, zacc, niacc, nhacc;
    racc[0]=br;  racc[1]=br;  racc[2]=br;  racc[3]=br;
    zacc[0]=bz;  zacc[1]=bz;  zacc[2]=bz;  zacc[3]=bz;
    niacc[0]=bn; niacc[1]=bn; niacc[2]=bn; niacc[3]=bn;
    nhacc[0]=bh_; nhacc[1]=bh_; nhacc[2]=bh_; nhacc[3]=bh_;
#pragma unroll
    for (int kk = 0; kk < 4; kk++) {
      racc  = __builtin_amdgcn_mfma_f32_16x16x32_bf16(ac[kk], bIHr[kk], racc, 0, 0, 0);
      racc  = __builtin_amdgcn_mfma_f32_16x16x32_bf16(ax[kk], bHHr[kk], racc, 0, 0, 0);
      zacc  = __builtin_amdgcn_mfma_f32_16x16x32_bf16(ac[kk], bIHz[kk], zacc, 0, 0, 0);
      zacc  = __builtin_amdgcn_mfma_f32_16x16x32_bf16(ax[kk], bHHz[kk], zacc, 0, 0, 0);
      niacc = __builtin_amdgcn_mfma_f32_16x16x32_bf16(ac[kk], bIHn[kk], niacc, 0, 0, 0);
      nhacc = __builtin_amdgcn_mfma_f32_16x16x32_bf16(ax[kk], bHHn[kk], nhacc, 0, 0, 0);
    }
#pragma unroll
    for (int r = 0; r < 4; r++) {
      const int vrow = t * 16 + quad * 4 + r;
      const float rg = 1.f / (1.f + __expf(-racc[r]));
      const float zg = 1.f / (1.f + __expf(-zacc[r]));
      const float n  = tanhf(niacc[r] + rg * nhacc[r]);
      const float xv = isb ? b2f(g_xbf[vrow * D_FEAT + h]) : xf32[vrow * D_FEAT + h];
      const float hn = (1.f - zg) * n + zg * xv;
      out[vrow * D_FEAT + h] = (hn < 0.f) ? 0.f : hn;  // relu; NaN passes (canary)
    }
  }
}

// ---------------- launch ------------------------------------------------------
extern "C" void kernel_launch(void* const* d_in, const int* in_sizes, int n_in,
                              void* d_out, int out_size, void* d_ws, size_t ws_size,
                              hipStream_t stream)
{
  (void)d_ws; (void)ws_size; (void)out_size;

  // resolve inputs by element count (same-size pairs keep dict order)
  int ix = -1, iWe = -1, ibe = -1, iWp = -1, ibp = -1,
      iWih = -1, iWhh = -1, ibih = -1, ibhh = -1, isrc = -1, idst = -1;
  for (int i = 0; i < n_in; i++) {
    const int s = in_sizes[i];
    if      (s == 6400000) ix = i;
    else if (s == 256)     iWe = i;
    else if (s == 1)       ibe = i;
    else if (s == 16384)   iWp = i;
    else if (s == 128)     ibp = i;
    else if (s == 49152)   { if (iWih < 0) iWih = i; else iWhh = i; }
    else if (s == 384)     { if (ibih < 0) ibih = i; else ibhh = i; }
    else if (s == 800000)  { if (isrc < 0) isrc = i; else idst = i; }
  }
  if (ix < 0 || iWe < 0 || ibe < 0 || iWp < 0 || ibp < 0 || iWih < 0 ||
      iWhh < 0 || ibih < 0 || ibhh < 0 || isrc < 0 || idst < 0) {
    ix = 0; iWe = 1; ibe = 2; iWp = 3; ibp = 4;           // dict-order fallback
    iWih = 5; iWhh = 6; ibih = 7; ibhh = 8; isrc = 9; idst = 10;
  }

  const int* src = (const int*)d_in[isrc];
  const int* dst = (const int*)d_in[idst];
  float* out = (float*)d_out;

  probe_kernel<<<1, 256, 0, stream>>>((const unsigned int*)d_in[ix]);
  conv_fused_kernel<<<CONV_X_BLOCKS + ZERO_BLOCKS + CONV_S_BLOCKS, 256, 0, stream>>>(
      d_in[ix],
      d_in[iWe], d_in[iWp], d_in[iWih], d_in[iWhh],
      d_in[ibe], d_in[ibp], d_in[ibih], d_in[ibhh]);
  np_hist_kernel<<<WS_BLOCKS + HIST_BLOCKS, 256, 0, stream>>>(dst);
  scan_a_kernel<<<SCAN_BLOCKS, 256, 0, stream>>>();
  scan_b_kernel<<<1, 256, 0, stream>>>();
  scan_c_kernel<<<SCAN_BLOCKS, 256, 0, stream>>>();
  edge_scatter_kernel<<<E_EDGES / 256, 256, 0, stream>>>(src, dst, E_EDGES);
  aggregate_kernel<<<V_NODES / 4, 256, 0, stream>>>();
  gru_kernel<<<WS_BLOCKS, 256, 0, stream>>>((const float*)d_in[ix], out);
}

// Round 11
// 259.426 us; speedup vs baseline: 2.0788x; 1.0970x over previous
//
#include <hip/hip_runtime.h>
#include <hip/hip_bf16.h>

// GNN attention layer. V=50000, E=800000, D=H=128. Inputs f32, OUTPUT f32.
//
// R11: edge_scatter was top (70 us): 800k cursor atomics + 2x4B random scatters
// (WRITE_SIZE 83 MB, 13x amplification). Fix: hist's atomicAdd already yields
// each edge's rank -> store g_rank in hist phase; scatter becomes atomic-free
// (pos = row_off[dst] + rank) with ONE combined 8B int2 write per edge.
// g_cursor eliminated. Rest = R10 (weight-stationary gru/np, 3-phase scan,
// fused conv, 4x-unrolled aggregate now reading int2 pairs).

#define V_NODES 50000
#define E_EDGES 800000
#define D_FEAT  128
#define NTILE   3125          // V/16
#define SCAN_BLOCKS 196       // ceil(50000/256)
#define GCHUNK  5             // tiles per wave-task (625 chunks x 8 cg = 5000 waves)
#define WS_BLOCKS 1250        // 5000 waves / 4 per block

typedef short bf16x8 __attribute__((ext_vector_type(8)));  // 8 bf16 in 4 VGPRs
typedef float f32x4  __attribute__((ext_vector_type(4)));
typedef unsigned short u16x4 __attribute__((ext_vector_type(4)));

// small-tensor bf16 pool element offsets
#define OFF_WEDGE 0
#define OFF_WPROJ 256
#define OFF_WIH   16640
#define OFF_WHH   65792
#define OFF_BEDGE 114944
#define OFF_BPROJ 114945
#define OFF_BIH   115073
#define OFF_BHH   115457
#define SMALL_TOTAL 115841
#define CONV_X_BLOCKS   6250   // 1.6M u16x4 / 256
#define ZERO_BLOCKS     196
#define CONV_S_BLOCKS   453
#define HIST_BLOCKS     3125   // 800000/256

// ---- device-global scratch (~46 MB; immune to ws_size) ----
__device__ int   g_is_bf16;
__device__ float g_pd[V_NODES];
__device__ float g_ps[V_NODES];
__device__ int   g_counts[V_NODES];
__device__ int   g_row_off[V_NODES + 1];
__device__ int   g_blocksum[SCAN_BLOCKS];
__device__ int   g_blockoff[SCAN_BLOCKS];
__device__ int   g_rank[E_EDGES];
__device__ __attribute__((aligned(16))) int2 g_s_pair[E_EDGES];  // {src, bits(w)}
__device__ __attribute__((aligned(16))) unsigned short g_xbf[V_NODES * D_FEAT];
__device__ __attribute__((aligned(16))) unsigned short g_wsmall[SMALL_TOTAL + 15];
__device__ __attribute__((aligned(16))) unsigned short g_hv[V_NODES * D_FEAT];
__device__ __attribute__((aligned(16))) unsigned short g_ctx[V_NODES * D_FEAT];

static __device__ __forceinline__ float b2f(unsigned short u) {
  union { unsigned int i; float f; } v; v.i = ((unsigned int)u) << 16; return v.f;
}
static __device__ __forceinline__ unsigned short f2b(float f) {
  unsigned int i = __float_as_uint(f);
  unsigned int r = (i + 0x7FFFu + ((i >> 16) & 1u)) >> 16;  // RNE (NaN stays NaN)
  return (unsigned short)r;
}
static __device__ __forceinline__ bf16x8 load_frag(const unsigned short* p) {
  return *reinterpret_cast<const bf16x8*>(p);  // 16B-aligned vector load
}

// ---------------- P: dtype probe on x ----------------------------------------
__global__ void probe_kernel(const unsigned int* __restrict__ x)
{
  __shared__ int cnt;
  if (threadIdx.x == 0) cnt = 0;
  __syncthreads();
  const unsigned int w  = x[threadIdx.x];
  const unsigned int lo = w & 0xFFFFu;
  const unsigned int ex = (lo >> 7) & 0xFFu;
  if (lo != 0u && ex >= 118u && ex <= 132u) atomicAdd(&cnt, 1);
  __syncthreads();
  if (threadIdx.x == 0) g_is_bf16 = (cnt >= 200) ? 1 : 0;
}

// ---------------- C: fused convert-x | zero-counts | convert-smalls ----------
__global__ void conv_fused_kernel(
    const void* __restrict__ x,
    const void* p0, const void* p1, const void* p2, const void* p3,
    const void* p4, const void* p5, const void* p6, const void* p7)
{
  const int b = blockIdx.x;
  if (b < CONV_X_BLOCKS) {
    const int t = b * 256 + threadIdx.x;
    if (g_is_bf16) {
      reinterpret_cast<u16x4*>(g_xbf)[t] = reinterpret_cast<const u16x4*>(x)[t];
    } else {
      const float4 v = reinterpret_cast<const float4*>(x)[t];
      u16x4 o; o.x = f2b(v.x); o.y = f2b(v.y); o.z = f2b(v.z); o.w = f2b(v.w);
      reinterpret_cast<u16x4*>(g_xbf)[t] = o;
    }
  } else if (b < CONV_X_BLOCKS + ZERO_BLOCKS) {
    const int i = (b - CONV_X_BLOCKS) * 256 + threadIdx.x;
    if (i < V_NODES) g_counts[i] = 0;
  } else {
    const int i = (b - CONV_X_BLOCKS - ZERO_BLOCKS) * 256 + threadIdx.x;
    if (i >= SMALL_TOTAL) return;
    const int offs[9] = {OFF_WEDGE, OFF_WPROJ, OFF_WIH, OFF_WHH,
                         OFF_BEDGE, OFF_BPROJ, OFF_BIH, OFF_BHH, SMALL_TOTAL};
    const void* ps[8] = {p0, p1, p2, p3, p4, p5, p6, p7};
    int r = 0;
#pragma unroll
    for (int k = 0; k < 8; k++) if (i >= offs[k]) r = k;
    const int j = i - offs[r];
    g_wsmall[i] = g_is_bf16
        ? reinterpret_cast<const unsigned short*>(ps[r])[j]
        : f2b(reinterpret_cast<const float*>(ps[r])[j]);
  }
}

// ---------------- K1: node_pre weight-stationary + hist(rank) ----------------
__global__ __launch_bounds__(256, 2) void np_hist_kernel(const int* __restrict__ dst)
{
  const int b = blockIdx.x;
  if (b >= WS_BLOCKS) {                      // ---- histogram + rank part ----
    const int e = (b - WS_BLOCKS) * 256 + threadIdx.x;
    if (e < E_EDGES) g_rank[e] = atomicAdd(&g_counts[dst[e]], 1);
    return;
  }
  // ---- node_pre: wave-task g -> col-group cg, tile chunk ----
  const int g     = b * 4 + (threadIdx.x >> 6);
  const int lane  = threadIdx.x & 63;
  const int cg    = g & 7;
  const int chunk = g >> 3;                  // [0, 625)
  const int col   = lane & 15;
  const int quad  = lane >> 4;
  const int h     = 16 * cg + col;

  // resident B fragments: W_proj rows [16cg, 16cg+16)
  bf16x8 bw[4];
#pragma unroll
  for (int kk = 0; kk < 4; kk++)
    bw[kk] = load_frag(g_wsmall + OFF_WPROJ + h * D_FEAT + kk * 32 + quad * 8);
  // cg 0 also owns the edge projections (cols 0/1 of W_edge)
  bf16x8 be[4];
#pragma unroll
  for (int kk = 0; kk < 4; kk++) { be[kk] = bf16x8{0,0,0,0,0,0,0,0}; }
  if (cg == 0 && col < 2) {
#pragma unroll
    for (int kk = 0; kk < 4; kk++)
      be[kk] = load_frag(g_wsmall + OFF_WEDGE + col * D_FEAT + kk * 32 + quad * 8);
  }
  const float bp = b2f(g_wsmall[OFF_BPROJ + h]);

  const int t0 = chunk * GCHUNK;
  for (int t = t0; t < t0 + GCHUNK; t++) {
    const int arow = t * 16 + col;
    bf16x8 a[4];
#pragma unroll
    for (int kk = 0; kk < 4; kk++)
      a[kk] = load_frag(g_xbf + arow * D_FEAT + kk * 32 + quad * 8);
    f32x4 acc; acc[0]=0.f; acc[1]=0.f; acc[2]=0.f; acc[3]=0.f;
#pragma unroll
    for (int kk = 0; kk < 4; kk++)
      acc = __builtin_amdgcn_mfma_f32_16x16x32_bf16(a[kk], bw[kk], acc, 0, 0, 0);
#pragma unroll
    for (int r = 0; r < 4; r++)
      g_hv[(t * 16 + quad * 4 + r) * D_FEAT + h] = f2b(acc[r] + bp);
    if (cg == 0) {
      f32x4 acce; acce[0]=0.f; acce[1]=0.f; acce[2]=0.f; acce[3]=0.f;
#pragma unroll
      for (int kk = 0; kk < 4; kk++)
        acce = __builtin_amdgcn_mfma_f32_16x16x32_bf16(a[kk], be[kk], acce, 0, 0, 0);
      if (col == 0) {
#pragma unroll
        for (int r = 0; r < 4; r++) g_pd[t * 16 + quad * 4 + r] = acce[r];
      } else if (col == 1) {
#pragma unroll
        for (int r = 0; r < 4; r++) g_ps[t * 16 + quad * 4 + r] = acce[r];
      }
    }
  }
}

// ---------------- K3a: block-local exclusive scan ----------------------------
__global__ __launch_bounds__(256) void scan_a_kernel()
{
  __shared__ int lds[256];
  const int b = blockIdx.x, t = threadIdx.x;
  const int idx = b * 256 + t;
  const int v = (idx < V_NODES) ? g_counts[idx] : 0;
  lds[t] = v;
  __syncthreads();
  for (int off = 1; off < 256; off <<= 1) {
    int tmp = (t >= off) ? lds[t - off] : 0;
    __syncthreads();
    lds[t] += tmp;
    __syncthreads();
  }
  if (idx < V_NODES) g_row_off[idx] = lds[t] - v;   // local exclusive prefix
  if (t == 255) g_blocksum[b] = lds[255];
}

// ---------------- K3b: scan the 196 block totals (1 small block) --------------
__global__ __launch_bounds__(256) void scan_b_kernel()
{
  __shared__ int lds[256];
  const int t = threadIdx.x;
  const int v = (t < SCAN_BLOCKS) ? g_blocksum[t] : 0;
  lds[t] = v;
  __syncthreads();
  for (int off = 1; off < 256; off <<= 1) {
    int tmp = (t >= off) ? lds[t - off] : 0;
    __syncthreads();
    lds[t] += tmp;
    __syncthreads();
  }
  if (t < SCAN_BLOCKS) g_blockoff[t] = lds[t] - v;
  if (t == 255) g_row_off[V_NODES] = lds[255];      // total = E
}

// ---------------- K3c: add block offsets -------------------------------------
__global__ __launch_bounds__(256) void scan_c_kernel()
{
  const int b = blockIdx.x, t = threadIdx.x;
  const int idx = b * 256 + t;
  if (idx >= V_NODES) return;
  g_row_off[idx] += g_blockoff[b];
}

// ---------------- K4: edge scatter — atomic-free, one 8B write/edge ----------
__global__ void edge_scatter_kernel(
    const int* __restrict__ src, const int* __restrict__ dst, int E)
{
  int e = blockIdx.x * blockDim.x + threadIdx.x;
  if (e >= E) return;
  const int d = dst[e], sn = src[e];
  float logit = g_pd[d] + g_ps[sn] + b2f(g_wsmall[OFF_BEDGE]);
  logit = (logit >= 0.f) ? logit : 0.01f * logit;           // LeakyReLU(0.01)
  const float w = __expf(logit);                            // no max-sub: cancels
  const int pos = g_row_off[d] + g_rank[e];
  g_s_pair[pos] = make_int2(sn, __float_as_int(w));
}

// ---------------- K5: aggregation, 4 nodes/block (one per wave) --------------
__global__ __launch_bounds__(256) void aggregate_kernel()
{
  const int v = blockIdx.x * 4 + (threadIdx.x >> 6);   // grid 12500 -> v < 50000
  const int lane = threadIdx.x & 63;                   // lane: cols 2l, 2l+1
  const int beg = g_row_off[v], end = g_row_off[v + 1];
  float accx = 0.f, accy = 0.f, ssum = 0.f;
  int i = beg;
  for (; i + 4 <= end; i += 4) {       // 4 gathers in flight
    const int2 q0 = g_s_pair[i],     q1 = g_s_pair[i + 1],
               q2 = g_s_pair[i + 2], q3 = g_s_pair[i + 3];
    const float w0 = __int_as_float(q0.y), w1 = __int_as_float(q1.y),
                w2 = __int_as_float(q2.y), w3 = __int_as_float(q3.y);
    const unsigned int p0 = *reinterpret_cast<const unsigned int*>(g_hv + q0.x * D_FEAT + lane * 2);
    const unsigned int p1 = *reinterpret_cast<const unsigned int*>(g_hv + q1.x * D_FEAT + lane * 2);
    const unsigned int p2 = *reinterpret_cast<const unsigned int*>(g_hv + q2.x * D_FEAT + lane * 2);
    const unsigned int p3 = *reinterpret_cast<const unsigned int*>(g_hv + q3.x * D_FEAT + lane * 2);
    ssum += (w0 + w1) + (w2 + w3);
    accx += w0 * b2f((unsigned short)(p0 & 0xFFFFu)) + w1 * b2f((unsigned short)(p1 & 0xFFFFu))
          + w2 * b2f((unsigned short)(p2 & 0xFFFFu)) + w3 * b2f((unsigned short)(p3 & 0xFFFFu));
    accy += w0 * b2f((unsigned short)(p0 >> 16)) + w1 * b2f((unsigned short)(p1 >> 16))
          + w2 * b2f((unsigned short)(p2 >> 16)) + w3 * b2f((unsigned short)(p3 >> 16));
  }
  for (; i < end; i++) {
    const int2 q = g_s_pair[i];
    const float w = __int_as_float(q.y);
    ssum += w;
    const unsigned int pair =
        *reinterpret_cast<const unsigned int*>(g_hv + q.x * D_FEAT + lane * 2);
    accx += w * b2f((unsigned short)(pair & 0xFFFFu));
    accy += w * b2f((unsigned short)(pair >> 16));
  }
  const float inv = (end > beg) ? (1.0f / ssum) : 0.0f;     // empty segment -> c=0
  float c0 = accx * inv, c1 = accy * inv;
  c0 = (c0 > 0.f) ? c0 : (__expf(c0) - 1.f);                // elu
  c1 = (c1 > 0.f) ? c1 : (__expf(c1) - 1.f);
  const unsigned int outp = ((unsigned int)f2b(c1) << 16) | (unsigned int)f2b(c0);
  *reinterpret_cast<unsigned int*>(g_ctx + v * D_FEAT + lane * 2) = outp;
}

// ---------------- K6: GRU weight-stationary (cg per wave, stream tiles) -------
__global__ __launch_bounds__(256, 2) void gru_kernel(const float* __restrict__ xf32,
                                                     float* __restrict__ out)
{
  const int g     = blockIdx.x * 4 + (threadIdx.x >> 6);
  const int lane  = threadIdx.x & 63;
  const int cg    = g & 7;
  const int chunk = g >> 3;                  // [0, 625)
  const int col   = lane & 15;
  const int quad  = lane >> 4;
  const int h     = 16 * cg + col;
  const unsigned short* W_ih = g_wsmall + OFF_WIH;
  const unsigned short* W_hh = g_wsmall + OFF_WHH;
  const int isb = g_is_bf16;

  // per-wave constant biases for columns h
  const float br  = b2f(g_wsmall[OFF_BIH + h])       + b2f(g_wsmall[OFF_BHH + h]);
  const float bz  = b2f(g_wsmall[OFF_BIH + 128 + h]) + b2f(g_wsmall[OFF_BHH + 128 + h]);
  const float bn  = b2f(g_wsmall[OFF_BIH + 256 + h]);
  const float bh_ = b2f(g_wsmall[OFF_BHH + 256 + h]);

  // resident B fragments: 24 frags = 96 VGPRs (launch_bounds(256,2) allows it)
  bf16x8 bIHr[4], bHHr[4], bIHz[4], bHHz[4], bIHn[4], bHHn[4];
#pragma unroll
  for (int kk = 0; kk < 4; kk++) {
    const int ko = kk * 32 + quad * 8;
    bIHr[kk] = load_frag(W_ih + h * D_FEAT + ko);
    bHHr[kk] = load_frag(W_hh + h * D_FEAT + ko);
    bIHz[kk] = load_frag(W_ih + (128 + h) * D_FEAT + ko);
    bHHz[kk] = load_frag(W_hh + (128 + h) * D_FEAT + ko);
    bIHn[kk] = load_frag(W_ih + (256 + h) * D_FEAT + ko);
    bHHn[kk] = load_frag(W_hh + (256 + h) * D_FEAT + ko);
  }

  const int t0 = chunk * GCHUNK;
  for (int t = t0; t < t0 + GCHUNK; t++) {
    const int arow = t * 16 + col;
    bf16x8 ax[4], ac[4];
#pragma unroll
    for (int kk = 0; kk < 4; kk++) {
      ax[kk] = load_frag(g_xbf + arow * D_FEAT + kk * 32 + quad * 8);
      ac[kk] = load_frag(g_ctx + arow * D_FEAT + kk * 32 + quad * 8);
    }
    f32x4 racc, zacc, niacc, nhacc;
    racc[0]=br;  racc[1]=br;  racc[2]=br;  racc[3]=br;
    zacc[0]=bz;  zacc[1]=bz;  zacc[2]=bz;  zacc[3]=bz;
    niacc[0]=bn; niacc[1]=bn; niacc[2]=bn; niacc[3]=bn;
    nhacc[0]=bh_; nhacc[1]=bh_; nhacc[2]=bh_; nhacc[3]=bh_;
#pragma unroll
    for (int kk = 0; kk < 4; kk++) {
      racc  = __builtin_amdgcn_mfma_f32_16x16x32_bf16(ac[kk], bIHr[kk], racc, 0, 0, 0);
      racc  = __builtin_amdgcn_mfma_f32_16x16x32_bf16(ax[kk], bHHr[kk], racc, 0, 0, 0);
      zacc  = __builtin_amdgcn_mfma_f32_16x16x32_bf16(ac[kk], bIHz[kk], zacc, 0, 0, 0);
      zacc  = __builtin_amdgcn_mfma_f32_16x16x32_bf16(ax[kk], bHHz[kk], zacc, 0, 0, 0);
      niacc = __builtin_amdgcn_mfma_f32_16x16x32_bf16(ac[kk], bIHn[kk], niacc, 0, 0, 0);
      nhacc = __builtin_amdgcn_mfma_f32_16x16x32_bf16(ax[kk], bHHn[kk], nhacc, 0, 0, 0);
    }
#pragma unroll
    for (int r = 0; r < 4; r++) {
      const int vrow = t * 16 + quad * 4 + r;
      const float rg = 1.f / (1.f + __expf(-racc[r]));
      const float zg = 1.f / (1.f + __expf(-zacc[r]));
      const float n  = tanhf(niacc[r] + rg * nhacc[r]);
      const float xv = isb ? b2f(g_xbf[vrow * D_FEAT + h]) : xf32[vrow * D_FEAT + h];
      const float hn = (1.f - zg) * n + zg * xv;
      out[vrow * D_FEAT + h] = (hn < 0.f) ? 0.f : hn;  // relu; NaN passes (canary)
    }
  }
}

// ---------------- launch ------------------------------------------------------
extern "C" void kernel_launch(void* const* d_in, const int* in_sizes, int n_in,
                              void* d_out, int out_size, void* d_ws, size_t ws_size,
                              hipStream_t stream)
{
  (void)d_ws; (void)ws_size; (void)out_size;

  // resolve inputs by element count (same-size pairs keep dict order)
  int ix = -1, iWe = -1, ibe = -1, iWp = -1, ibp = -1,
      iWih = -1, iWhh = -1, ibih = -1, ibhh = -1, isrc = -1, idst = -1;
  for (int i = 0; i < n_in; i++) {
    const int s = in_sizes[i];
    if      (s == 6400000) ix = i;
    else if (s == 256)     iWe = i;
    else if (s == 1)       ibe = i;
    else if (s == 16384)   iWp = i;
    else if (s == 128)     ibp = i;
    else if (s == 49152)   { if (iWih < 0) iWih = i; else iWhh = i; }
    else if (s == 384)     { if (ibih < 0) ibih = i; else ibhh = i; }
    else if (s == 800000)  { if (isrc < 0) isrc = i; else idst = i; }
  }
  if (ix < 0 || iWe < 0 || ibe < 0 || iWp < 0 || ibp < 0 || iWih < 0 ||
      iWhh < 0 || ibih < 0 || ibhh < 0 || isrc < 0 || idst < 0) {
    ix = 0; iWe = 1; ibe = 2; iWp = 3; ibp = 4;           // dict-order fallback
    iWih = 5; iWhh = 6; ibih = 7; ibhh = 8; isrc = 9; idst = 10;
  }

  const int* src = (const int*)d_in[isrc];
  const int* dst = (const int*)d_in[idst];
  float* out = (float*)d_out;

  probe_kernel<<<1, 256, 0, stream>>>((const unsigned int*)d_in[ix]);
  conv_fused_kernel<<<CONV_X_BLOCKS + ZERO_BLOCKS + CONV_S_BLOCKS, 256, 0, stream>>>(
      d_in[ix],
      d_in[iWe], d_in[iWp], d_in[iWih], d_in[iWhh],
      d_in[ibe], d_in[ibp], d_in[ibih], d_in[ibhh]);
  np_hist_kernel<<<WS_BLOCKS + HIST_BLOCKS, 256, 0, stream>>>(dst);
  scan_a_kernel<<<SCAN_BLOCKS, 256, 0, stream>>>();
  scan_b_kernel<<<1, 256, 0, stream>>>();
  scan_c_kernel<<<SCAN_BLOCKS, 256, 0, stream>>>();
  edge_scatter_kernel<<<E_EDGES / 256, 256, 0, stream>>>(src, dst, E_EDGES);
  aggregate_kernel<<<V_NODES / 4, 256, 0, stream>>>();
  gru_kernel<<<WS_BLOCKS, 256, 0, stream>>>((const float*)d_in[ix], out);
}